// Round 1
// baseline (5163.878 us; speedup 1.0000x reference)
//
#include <hip/hip_runtime.h>
#include <math.h>

#define E_DIM 1024
#define ROWS  4096   // B*S
#define SEQ   2048
#define NB    2

// ---------------- weight abs-mean (two-stage, deterministic) ----------------
__global__ void absmean_stage1(const float* __restrict__ W0, const float* __restrict__ W1,
                               const float* __restrict__ W2, const float* __restrict__ W3,
                               float* __restrict__ partials) {
  int y = blockIdx.y;
  const float* W = (y == 0) ? W0 : (y == 1) ? W1 : (y == 2) ? W2 : W3;
  int n = (y == 0 || y == 3) ? (1024 * 1024) : (256 * 1024);
  int tid = threadIdx.x;
  float s = 0.f;
  for (int i = blockIdx.x * 256 + tid; i < n; i += 256 * 256) s += fabsf(W[i]);
  __shared__ float red[256];
  red[tid] = s; __syncthreads();
  for (int w = 128; w > 0; w >>= 1) { if (tid < w) red[tid] += red[tid + w]; __syncthreads(); }
  if (tid == 0) partials[y * 256 + blockIdx.x] = red[0];
}

__global__ void absmean_stage2(const float* __restrict__ partials, float* __restrict__ alphas) {
  int y = blockIdx.x; int tid = threadIdx.x;
  __shared__ float red[256];
  red[tid] = partials[y * 256 + tid]; __syncthreads();
  for (int w = 128; w > 0; w >>= 1) { if (tid < w) red[tid] += red[tid + w]; __syncthreads(); }
  int n = (y == 0 || y == 3) ? (1024 * 1024) : (256 * 1024);
  if (tid == 0) alphas[y] = red[0] / (float)n;
}

// ---------------- sign + transpose: W[O][E] -> sign(W)^T [E][O] fp32 ----------------
__global__ void sign_transpose(const float* __restrict__ W, float* __restrict__ WsT,
                               int O, int Edim) {
  __shared__ float t[64][65];
  int o0 = blockIdx.x * 64, e0 = blockIdx.y * 64;
  int j = threadIdx.x & 63, i0 = threadIdx.x >> 6;   // 256 threads
  #pragma unroll
  for (int k = 0; k < 16; k++) {
    int i = k * 4 + i0;
    t[i][j] = W[(size_t)(o0 + i) * Edim + e0 + j];   // coalesced in e
  }
  __syncthreads();
  #pragma unroll
  for (int k = 0; k < 16; k++) {
    int i = k * 4 + i0;                               // e-offset
    float w = t[j][i];                                // = W[o0+j][e0+i]
    float sgn = (w > 0.f) ? 1.f : ((w < 0.f) ? -1.f : 0.f);
    WsT[(size_t)(e0 + i) * O + o0 + j] = sgn;         // coalesced in o
  }
}

// ---------------- RMSNorm + activation quant -> int8 + per-row dequant scale ----------------
__global__ void act_quant(const float* __restrict__ X, signed char* __restrict__ Q,
                          float* __restrict__ inv_s) {
  int r = blockIdx.x; int tid = threadIdx.x;
  const float* x = X + (size_t)r * 1024;
  float4 v = ((const float4*)x)[tid];
  float ss = v.x * v.x + v.y * v.y + v.z * v.z + v.w * v.w;
  float am = fmaxf(fmaxf(fabsf(v.x), fabsf(v.y)), fmaxf(fabsf(v.z), fabsf(v.w)));
  __shared__ float rs[256], rm[256];
  rs[tid] = ss; rm[tid] = am; __syncthreads();
  for (int w = 128; w > 0; w >>= 1) {
    if (tid < w) { rs[tid] += rs[tid + w]; rm[tid] = fmaxf(rm[tid], rm[tid + w]); }
    __syncthreads();
  }
  __shared__ float s_mul, s_inv;
  if (tid == 0) {
    float rms = sqrtf(rs[0] * (1.f / 1024.f) + 1e-6f);
    float inv_rms = 1.f / rms;
    float maxn = rm[0] * inv_rms * 0.03125f;          // max |x_norm|
    float cm = fmaxf(maxn, 1e-5f);
    float scale = 127.f / cm;
    s_mul = inv_rms * 0.03125f * scale;               // x -> x_norm*scale
    s_inv = cm / 127.f;                               // dequant factor
  }
  __syncthreads();
  float mul = s_mul;
  float q0 = fminf(fmaxf(rintf(v.x * mul), -128.f), 127.f);
  float q1 = fminf(fmaxf(rintf(v.y * mul), -128.f), 127.f);
  float q2 = fminf(fmaxf(rintf(v.z * mul), -128.f), 127.f);
  float q3 = fminf(fmaxf(rintf(v.w * mul), -128.f), 127.f);
  int i0 = (int)q0, i1 = (int)q1, i2 = (int)q2, i3 = (int)q3;
  int packed = (i0 & 0xff) | ((i1 & 0xff) << 8) | ((i2 & 0xff) << 16) | ((i3 & 0xff) << 24);
  *(int*)(Q + (size_t)r * 1024 + tid * 4) = packed;
  if (tid == 0) inv_s[r] = s_inv;
}

// ---------------- bit GEMM: out[r][o] = alpha*inv_s[r]*sum_e A8[r][e]*signW[e][o] + bias[o] ----
template <int OT>
__global__ void bit_gemm(const signed char* __restrict__ A, const float* __restrict__ WsT,
                         const float* __restrict__ bias, const float* __restrict__ inv_s,
                         const float* __restrict__ alphas, int aidx, int O,
                         float* __restrict__ Out) {
  int r = blockIdx.x * 64 + threadIdx.x;
  int o0 = blockIdx.y * OT;
  float acc[OT];
  #pragma unroll
  for (int i = 0; i < OT; i++) acc[i] = 0.f;
  const signed char* a = A + (size_t)r * 1024;
  for (int e0 = 0; e0 < 1024; e0 += 4) {
    int pack = *(const int*)(a + e0);
    float a0 = (float)((signed char)(pack));
    float a1 = (float)((signed char)(pack >> 8));
    float a2 = (float)((signed char)(pack >> 16));
    float a3 = (float)((signed char)(pack >> 24));
    const float* w0 = WsT + (size_t)e0 * O + o0;      // block-uniform -> s_load
    const float* w1 = w0 + O;
    const float* w2 = w0 + 2 * O;
    const float* w3 = w0 + 3 * O;
    #pragma unroll
    for (int jj = 0; jj < OT; jj++)
      acc[jj] += a0 * w0[jj] + a1 * w1[jj] + a2 * w2[jj] + a3 * w3[jj];
  }
  float f = alphas[aidx] * inv_s[r];
  #pragma unroll
  for (int jj = 0; jj < OT; jj++)
    Out[(size_t)r * O + o0 + jj] = f * acc[jj] + bias[o0 + jj];
}

// ---------------- GQA attention, fp32, thread-per-query, uniform K/V loads ----------------
__global__ void gqa_attn(const float* __restrict__ Qb, const float* __restrict__ Kb,
                         const float* __restrict__ Vb, float* __restrict__ Xb) {
  int q_idx = blockIdx.x * 64 + threadIdx.x;   // 0..2047
  int bh = blockIdx.y;
  int b = bh >> 4, h = bh & 15, g = h >> 2;
  const float* qp = Qb + ((size_t)(b * SEQ + q_idx)) * 1024 + h * 64;
  float qreg[64];
  #pragma unroll
  for (int i = 0; i < 16; i++) {
    float4 t = ((const float4*)qp)[i];
    qreg[4 * i + 0] = t.x * 0.125f; qreg[4 * i + 1] = t.y * 0.125f;
    qreg[4 * i + 2] = t.z * 0.125f; qreg[4 * i + 3] = t.w * 0.125f;
  }
  float acc[64];
  #pragma unroll
  for (int d = 0; d < 64; d++) acc[d] = 0.f;
  float l = 0.f;
  const float* kbase = Kb + (size_t)b * SEQ * 256 + g * 64;
  const float* vbase = Vb + (size_t)b * SEQ * 256 + g * 64;
  for (int j = 0; j < SEQ; j++) {
    const float* kp = kbase + (size_t)j * 256;        // block-uniform -> s_load
    float s0 = 0.f, s1 = 0.f, s2 = 0.f, s3 = 0.f;
    #pragma unroll
    for (int d = 0; d < 64; d += 4) {
      s0 += qreg[d + 0] * kp[d + 0];
      s1 += qreg[d + 1] * kp[d + 1];
      s2 += qreg[d + 2] * kp[d + 2];
      s3 += qreg[d + 3] * kp[d + 3];
    }
    float p = __expf((s0 + s1) + (s2 + s3));          // scores are O(1e-3): no max-subtract needed
    l += p;
    const float* vp = vbase + (size_t)j * 256;        // block-uniform -> s_load
    #pragma unroll
    for (int d = 0; d < 64; d++) acc[d] += p * vp[d];
  }
  float inv = 1.f / l;
  float* xp = Xb + ((size_t)(b * SEQ + q_idx)) * 1024 + h * 64;
  #pragma unroll
  for (int i = 0; i < 16; i++) {
    float4 t;
    t.x = acc[4 * i + 0] * inv; t.y = acc[4 * i + 1] * inv;
    t.z = acc[4 * i + 2] * inv; t.w = acc[4 * i + 3] * inv;
    ((float4*)xp)[i] = t;
  }
}

extern "C" void kernel_launch(void* const* d_in, const int* in_sizes, int n_in,
                              void* d_out, int out_size, void* d_ws, size_t ws_size,
                              hipStream_t stream) {
  const float* query = (const float*)d_in[0];
  const float* key   = (const float*)d_in[1];
  const float* value = (const float*)d_in[2];
  const float* Wq = (const float*)d_in[3];
  const float* bq = (const float*)d_in[4];
  const float* Wk = (const float*)d_in[5];
  const float* bk = (const float*)d_in[6];
  const float* Wv = (const float*)d_in[7];
  const float* bv = (const float*)d_in[8];
  const float* Wo = (const float*)d_in[9];
  const float* bo = (const float*)d_in[10];
  float* out = (float*)d_out;

  char* ws = (char*)d_ws;
  size_t off = 0;
  auto alloc = [&](size_t b) { size_t o = off; off += (b + 255) & ~(size_t)255; return o; };
  float* alphas   = (float*)(ws + alloc(16));
  float* partials = (float*)(ws + alloc(4 * 256 * 4));
  float* swq = (float*)(ws + alloc((size_t)1024 * 1024 * 4));
  float* swk = (float*)(ws + alloc((size_t)1024 * 256 * 4));
  float* swv = (float*)(ws + alloc((size_t)1024 * 256 * 4));
  float* swo = (float*)(ws + alloc((size_t)1024 * 1024 * 4));
  float* invs = (float*)(ws + alloc(4 * 4096 * 4));
  signed char* xq0 = (signed char*)(ws + alloc((size_t)ROWS * 1024));
  signed char* xq1 = (signed char*)(ws + alloc((size_t)ROWS * 1024));
  signed char* xq2 = (signed char*)(ws + alloc((size_t)ROWS * 1024));
  signed char* xq3 = xq0;  // reuse: xq0 consumed before attention output quant
  float* qbuf = (float*)(ws + alloc((size_t)ROWS * 1024 * 4));
  float* kbuf = (float*)(ws + alloc((size_t)ROWS * 256 * 4));
  float* vbuf = (float*)(ws + alloc((size_t)ROWS * 256 * 4));
  float* xbuf = (float*)(ws + alloc((size_t)ROWS * 1024 * 4));

  absmean_stage1<<<dim3(256, 4), 256, 0, stream>>>(Wq, Wk, Wv, Wo, partials);
  absmean_stage2<<<4, 256, 0, stream>>>(partials, alphas);

  sign_transpose<<<dim3(16, 16), 256, 0, stream>>>(Wq, swq, 1024, 1024);
  sign_transpose<<<dim3(4, 16),  256, 0, stream>>>(Wk, swk, 256, 1024);
  sign_transpose<<<dim3(4, 16),  256, 0, stream>>>(Wv, swv, 256, 1024);
  sign_transpose<<<dim3(16, 16), 256, 0, stream>>>(Wo, swo, 1024, 1024);

  act_quant<<<ROWS, 256, 0, stream>>>(query, xq0, invs + 0 * 4096);
  act_quant<<<ROWS, 256, 0, stream>>>(key,   xq1, invs + 1 * 4096);
  act_quant<<<ROWS, 256, 0, stream>>>(value, xq2, invs + 2 * 4096);

  bit_gemm<64><<<dim3(64, 16), 64, 0, stream>>>(xq0, swq, bq, invs + 0 * 4096, alphas, 0, 1024, qbuf);
  bit_gemm<32><<<dim3(64, 8),  64, 0, stream>>>(xq1, swk, bk, invs + 1 * 4096, alphas, 1, 256, kbuf);
  bit_gemm<32><<<dim3(64, 8),  64, 0, stream>>>(xq2, swv, bv, invs + 2 * 4096, alphas, 2, 256, vbuf);

  gqa_attn<<<dim3(32, 32), 64, 0, stream>>>(qbuf, kbuf, vbuf, xbuf);

  act_quant<<<ROWS, 256, 0, stream>>>(xbuf, xq3, invs + 3 * 4096);
  bit_gemm<64><<<dim3(64, 16), 64, 0, stream>>>(xq3, swo, bo, invs + 3 * 4096, alphas, 3, 1024, out);
}

// Round 2
// 432.271 us; speedup vs baseline: 11.9459x; 11.9459x over previous
//
#include <hip/hip_runtime.h>
#include <math.h>

typedef short bf16x8 __attribute__((ext_vector_type(8)));
typedef float f32x4 __attribute__((ext_vector_type(4)));

__device__ inline unsigned short f2bf_rtn(float x) {
  unsigned u = __float_as_uint(x);
  u += 0x7fffu + ((u >> 16) & 1u);
  return (unsigned short)(u >> 16);
}
__device__ inline unsigned short f2bf_trunc(float x) {  // exact for small-int-valued floats
  return (unsigned short)(__float_as_uint(x) >> 16);
}

// ---------------- weight abs-mean (two-stage, deterministic) ----------------
__global__ void absmean_stage1(const float* __restrict__ W0, const float* __restrict__ W1,
                               const float* __restrict__ W2, const float* __restrict__ W3,
                               float* __restrict__ partials) {
  int y = blockIdx.y;
  const float* W = (y == 0) ? W0 : (y == 1) ? W1 : (y == 2) ? W2 : W3;
  int n = (y == 0 || y == 3) ? (1024 * 1024) : (256 * 1024);
  int tid = threadIdx.x;
  float s = 0.f;
  for (int i = blockIdx.x * 256 + tid; i < n; i += 256 * 256) s += fabsf(W[i]);
  __shared__ float red[256];
  red[tid] = s; __syncthreads();
  for (int w = 128; w > 0; w >>= 1) { if (tid < w) red[tid] += red[tid + w]; __syncthreads(); }
  if (tid == 0) partials[y * 256 + blockIdx.x] = red[0];
}

__global__ void absmean_stage2(const float* __restrict__ partials, float* __restrict__ alphas) {
  int y = blockIdx.x; int tid = threadIdx.x;
  __shared__ float red[256];
  red[tid] = partials[y * 256 + tid]; __syncthreads();
  for (int w = 128; w > 0; w >>= 1) { if (tid < w) red[tid] += red[tid + w]; __syncthreads(); }
  int n = (y == 0 || y == 3) ? (1024 * 1024) : (256 * 1024);
  if (tid == 0) alphas[y] = red[0] / (float)n;
}

// ---------------- sign(W) -> bf16 (+1/-1/0), same [O][E] layout ----------------
__global__ void w_sign_bf16(const float* __restrict__ W, unsigned short* __restrict__ S) {
  int i = blockIdx.x * 256 + threadIdx.x;   // one float4 per thread
  float4 v = ((const float4*)W)[i];
  unsigned short s0 = (v.x > 0.f) ? 0x3F80 : (v.x < 0.f ? 0xBF80 : 0);
  unsigned short s1 = (v.y > 0.f) ? 0x3F80 : (v.y < 0.f ? 0xBF80 : 0);
  unsigned short s2 = (v.z > 0.f) ? 0x3F80 : (v.z < 0.f ? 0xBF80 : 0);
  unsigned short s3 = (v.w > 0.f) ? 0x3F80 : (v.w < 0.f ? 0xBF80 : 0);
  uint2 o;
  o.x = (unsigned)s0 | ((unsigned)s1 << 16);
  o.y = (unsigned)s2 | ((unsigned)s3 << 16);
  ((uint2*)S)[i] = o;
}

// ---------------- RMSNorm + activation quant -> bf16 ints + per-row dequant scale ----------------
__global__ void act_quant(const float* __restrict__ X, unsigned short* __restrict__ Q,
                          float* __restrict__ inv_s) {
  int r = blockIdx.x; int tid = threadIdx.x;
  const float* x = X + (size_t)r * 1024;
  float4 v = ((const float4*)x)[tid];
  float ss = v.x * v.x + v.y * v.y + v.z * v.z + v.w * v.w;
  float am = fmaxf(fmaxf(fabsf(v.x), fabsf(v.y)), fmaxf(fabsf(v.z), fabsf(v.w)));
  __shared__ float rs[256], rm[256];
  rs[tid] = ss; rm[tid] = am; __syncthreads();
  for (int w = 128; w > 0; w >>= 1) {
    if (tid < w) { rs[tid] += rs[tid + w]; rm[tid] = fmaxf(rm[tid], rm[tid + w]); }
    __syncthreads();
  }
  __shared__ float s_mul, s_inv;
  if (tid == 0) {
    float rms = sqrtf(rs[0] * (1.f / 1024.f) + 1e-6f);
    float inv_rms = 1.f / rms;
    float maxn = rm[0] * inv_rms * 0.03125f;          // max |x_norm|
    float cm = fmaxf(maxn, 1e-5f);
    float scale = 127.f / cm;
    s_mul = inv_rms * 0.03125f * scale;               // x -> x_norm*scale
    s_inv = cm / 127.f;                               // dequant factor
  }
  __syncthreads();
  float mul = s_mul;
  float q0 = fminf(fmaxf(rintf(v.x * mul), -128.f), 127.f);
  float q1 = fminf(fmaxf(rintf(v.y * mul), -128.f), 127.f);
  float q2 = fminf(fmaxf(rintf(v.z * mul), -128.f), 127.f);
  float q3 = fminf(fmaxf(rintf(v.w * mul), -128.f), 127.f);
  uint2 o;
  o.x = (unsigned)f2bf_trunc(q0) | ((unsigned)f2bf_trunc(q1) << 16);
  o.y = (unsigned)f2bf_trunc(q2) | ((unsigned)f2bf_trunc(q3) << 16);
  ((uint2*)(Q + (size_t)r * 1024))[tid] = o;
  if (tid == 0) inv_s[r] = s_inv;
}

// ---------------- bf16 MFMA bit-GEMM (exact: integer values in bf16) ----------------
// A [4096][1024] bf16 int-valued; Wb [N][1024] bf16 sign; out[r][o]=alpha*inv_s[r]*sum+bias[o]
__global__ __launch_bounds__(256) void gemm_bf16(
    const unsigned short* __restrict__ A, const unsigned short* __restrict__ Wb,
    const float* __restrict__ bias, const float* __restrict__ inv_s,
    const float* __restrict__ alphas, int aidx, int N, float* __restrict__ Out) {
  int lane = threadIdx.x & 63, wid = threadIdx.x >> 6;
  int rb = blockIdx.x * 128 + wid * 32;
  int cb = blockIdx.y * 64;
  int lm = lane & 15, lk = (lane >> 4) * 8;
  f32x4 zero = {0.f, 0.f, 0.f, 0.f};
  f32x4 acc[2][4];
  #pragma unroll
  for (int i = 0; i < 2; i++)
    #pragma unroll
    for (int j = 0; j < 4; j++) acc[i][j] = zero;
  const unsigned short* a0p = A + (size_t)(rb + lm) * 1024 + lk;
  const unsigned short* a1p = a0p + 16 * 1024;
  const unsigned short* b0p = Wb + (size_t)(cb + lm) * 1024 + lk;
  #pragma unroll 8
  for (int kk = 0; kk < 32; kk++) {
    bf16x8 a0 = *(const bf16x8*)(a0p + kk * 32);
    bf16x8 a1 = *(const bf16x8*)(a1p + kk * 32);
    #pragma unroll
    for (int ni = 0; ni < 4; ni++) {
      bf16x8 b = *(const bf16x8*)(b0p + (size_t)ni * 16 * 1024 + kk * 32);
      acc[0][ni] = __builtin_amdgcn_mfma_f32_16x16x32_bf16(a0, b, acc[0][ni], 0, 0, 0);
      acc[1][ni] = __builtin_amdgcn_mfma_f32_16x16x32_bf16(a1, b, acc[1][ni], 0, 0, 0);
    }
  }
  float al = alphas[aidx];
  int lh4 = (lane >> 4) * 4;
  #pragma unroll
  for (int mi = 0; mi < 2; mi++) {
    #pragma unroll
    for (int r = 0; r < 4; r++) {
      int row = rb + mi * 16 + lh4 + r;
      float f = al * inv_s[row];
      #pragma unroll
      for (int ni = 0; ni < 4; ni++) {
        int col = cb + ni * 16 + lm;
        Out[(size_t)row * N + col] = f * acc[mi][ni][r] + bias[col];
      }
    }
  }
}

// ---------------- V column sums per (b,g): Vsum[bg][d] = sum_t V[t][d] ----------------
__global__ void v_colsum(const float* __restrict__ Vb, float* __restrict__ Vsum) {
  int bg = blockIdx.x;              // 0..7
  int b = bg >> 2, g = bg & 3;
  int tid = threadIdx.x;            // 256
  int d = tid & 63, s = tid >> 6;
  const float* base = Vb + (size_t)b * 2048 * 256 + g * 64 + d;
  float sum = 0.f;
  for (int t = s * 512; t < s * 512 + 512; t++) sum += base[(size_t)t * 256];
  __shared__ float red[256];
  red[tid] = sum; __syncthreads();
  if (tid < 64) Vsum[bg * 64 + d] = red[d] + red[64 + d] + red[128 + d] + red[192 + d];
}

// ---------------- GQA attention: bf16 MFMA flash-style with P=exp(s)-1 trick ----------------
#define APAD 72
__global__ __launch_bounds__(256) void attn_mfma(
    const float* __restrict__ Qb, const float* __restrict__ Kb, const float* __restrict__ Vb,
    const float* __restrict__ Vsum, float* __restrict__ Xb) {
  __shared__ __align__(16) unsigned short Kl[64 * APAD];
  __shared__ __align__(16) unsigned short Vt[64 * APAD];
  __shared__ __align__(16) unsigned short Pl[4 * 32 * APAD];
  int tid = threadIdx.x, lane = tid & 63, wid = tid >> 6;
  int bh = blockIdx.y; int b = bh >> 4, h = bh & 15, g = h >> 2;
  int qt0 = blockIdx.x * 128;
  int lm = lane & 15, lh = lane >> 4;

  // Q fragments (scale 0.125 folded in; exact pow2 multiply)
  bf16x8 qf[2][2];
  const float* qrow = Qb + (size_t)(b * 2048 + qt0 + wid * 32 + lm) * 1024 + h * 64 + lh * 8;
  #pragma unroll
  for (int mi = 0; mi < 2; mi++)
    #pragma unroll
    for (int kk = 0; kk < 2; kk++) {
      const float* p = qrow + mi * 16 * 1024 + kk * 32;
      float4 x0 = *(const float4*)p;
      float4 x1 = *(const float4*)(p + 4);
      union { bf16x8 v; unsigned short u[8]; } t;
      t.u[0] = f2bf_rtn(x0.x * 0.125f); t.u[1] = f2bf_rtn(x0.y * 0.125f);
      t.u[2] = f2bf_rtn(x0.z * 0.125f); t.u[3] = f2bf_rtn(x0.w * 0.125f);
      t.u[4] = f2bf_rtn(x1.x * 0.125f); t.u[5] = f2bf_rtn(x1.y * 0.125f);
      t.u[6] = f2bf_rtn(x1.z * 0.125f); t.u[7] = f2bf_rtn(x1.w * 0.125f);
      qf[mi][kk] = t.v;
    }

  f32x4 zero = {0.f, 0.f, 0.f, 0.f};
  f32x4 acc[2][4];
  #pragma unroll
  for (int i = 0; i < 2; i++)
    #pragma unroll
    for (int j = 0; j < 4; j++) acc[i][j] = zero;
  float rsum[2][4] = {{0.f,0.f,0.f,0.f},{0.f,0.f,0.f,0.f}};

  int st_t = tid >> 2, st_d = (tid & 3) * 16;
  unsigned short* pw = Pl + wid * 32 * APAD;

  for (int t0 = 0; t0 < 2048; t0 += 64) {
    __syncthreads();
    // ---- stage K (row-major) and V (transposed) as bf16 ----
    {
      const float* kp = Kb + (size_t)(b * 2048 + t0 + st_t) * 256 + g * 64 + st_d;
      const float* vp = Vb + (size_t)(b * 2048 + t0 + st_t) * 256 + g * 64 + st_d;
      float4 ka = *(const float4*)(kp);
      float4 kb = *(const float4*)(kp + 4);
      float4 kc = *(const float4*)(kp + 8);
      float4 kd = *(const float4*)(kp + 12);
      union { bf16x8 v; unsigned short u[8]; } kl0, kl1;
      kl0.u[0] = f2bf_rtn(ka.x); kl0.u[1] = f2bf_rtn(ka.y); kl0.u[2] = f2bf_rtn(ka.z); kl0.u[3] = f2bf_rtn(ka.w);
      kl0.u[4] = f2bf_rtn(kb.x); kl0.u[5] = f2bf_rtn(kb.y); kl0.u[6] = f2bf_rtn(kb.z); kl0.u[7] = f2bf_rtn(kb.w);
      kl1.u[0] = f2bf_rtn(kc.x); kl1.u[1] = f2bf_rtn(kc.y); kl1.u[2] = f2bf_rtn(kc.z); kl1.u[3] = f2bf_rtn(kc.w);
      kl1.u[4] = f2bf_rtn(kd.x); kl1.u[5] = f2bf_rtn(kd.y); kl1.u[6] = f2bf_rtn(kd.z); kl1.u[7] = f2bf_rtn(kd.w);
      *(bf16x8*)(&Kl[st_t * APAD + st_d]) = kl0.v;
      *(bf16x8*)(&Kl[st_t * APAD + st_d + 8]) = kl1.v;
      float4 va = *(const float4*)(vp);
      float4 vb = *(const float4*)(vp + 4);
      float4 vc = *(const float4*)(vp + 8);
      float4 vd = *(const float4*)(vp + 12);
      unsigned short vu[16];
      vu[0]=f2bf_rtn(va.x); vu[1]=f2bf_rtn(va.y); vu[2]=f2bf_rtn(va.z); vu[3]=f2bf_rtn(va.w);
      vu[4]=f2bf_rtn(vb.x); vu[5]=f2bf_rtn(vb.y); vu[6]=f2bf_rtn(vb.z); vu[7]=f2bf_rtn(vb.w);
      vu[8]=f2bf_rtn(vc.x); vu[9]=f2bf_rtn(vc.y); vu[10]=f2bf_rtn(vc.z); vu[11]=f2bf_rtn(vc.w);
      vu[12]=f2bf_rtn(vd.x); vu[13]=f2bf_rtn(vd.y); vu[14]=f2bf_rtn(vd.z); vu[15]=f2bf_rtn(vd.w);
      #pragma unroll
      for (int j = 0; j < 16; j++) Vt[(st_d + j) * APAD + st_t] = vu[j];
    }
    __syncthreads();

    // ---- S = Q K^T (16x16x32 MFMA) ----
    f32x4 s[2][4];
    #pragma unroll
    for (int i = 0; i < 2; i++)
      #pragma unroll
      for (int j = 0; j < 4; j++) s[i][j] = zero;
    #pragma unroll
    for (int kk = 0; kk < 2; kk++) {
      #pragma unroll
      for (int ni = 0; ni < 4; ni++) {
        bf16x8 kf = *(const bf16x8*)(&Kl[(ni * 16 + lm) * APAD + kk * 32 + lh * 8]);
        s[0][ni] = __builtin_amdgcn_mfma_f32_16x16x32_bf16(qf[0][kk], kf, s[0][ni], 0, 0, 0);
        s[1][ni] = __builtin_amdgcn_mfma_f32_16x16x32_bf16(qf[1][kk], kf, s[1][ni], 0, 0, 0);
      }
    }

    // ---- P~ = exp(s)-1 -> LDS (bf16), accumulate row sums in fp32 ----
    #pragma unroll
    for (int mi = 0; mi < 2; mi++)
      #pragma unroll
      for (int ni = 0; ni < 4; ni++)
        #pragma unroll
        for (int r = 0; r < 4; r++) {
          float pt = __expf(s[mi][ni][r]) - 1.0f;
          rsum[mi][r] += pt;
          pw[(mi * 16 + lh * 4 + r) * APAD + ni * 16 + lm] = f2bf_rtn(pt);
        }

    // ---- acc += P~ * V ----
    #pragma unroll
    for (int kk = 0; kk < 2; kk++) {
      bf16x8 pa0 = *(const bf16x8*)(pw + (lm) * APAD + kk * 32 + lh * 8);
      bf16x8 pa1 = *(const bf16x8*)(pw + (16 + lm) * APAD + kk * 32 + lh * 8);
      #pragma unroll
      for (int di = 0; di < 4; di++) {
        bf16x8 vf = *(const bf16x8*)(&Vt[(di * 16 + lm) * APAD + kk * 32 + lh * 8]);
        acc[0][di] = __builtin_amdgcn_mfma_f32_16x16x32_bf16(pa0, vf, acc[0][di], 0, 0, 0);
        acc[1][di] = __builtin_amdgcn_mfma_f32_16x16x32_bf16(pa1, vf, acc[1][di], 0, 0, 0);
      }
    }
  }

  // ---- epilogue: out = (acc + Vsum) / (2048 + rowsum) ----
  const float* vs = Vsum + (b * 4 + g) * 64;
  #pragma unroll
  for (int mi = 0; mi < 2; mi++) {
    #pragma unroll
    for (int r = 0; r < 4; r++) {
      float v = rsum[mi][r];
      v += __shfl_xor(v, 1); v += __shfl_xor(v, 2);
      v += __shfl_xor(v, 4); v += __shfl_xor(v, 8);
      float inv = 1.0f / (2048.0f + v);
      int row = qt0 + wid * 32 + mi * 16 + lh * 4 + r;
      float* op = Xb + (size_t)(b * 2048 + row) * 1024 + h * 64;
      #pragma unroll
      for (int di = 0; di < 4; di++)
        op[di * 16 + lm] = (acc[mi][di][r] + vs[di * 16 + lm]) * inv;
    }
  }
}

extern "C" void kernel_launch(void* const* d_in, const int* in_sizes, int n_in,
                              void* d_out, int out_size, void* d_ws, size_t ws_size,
                              hipStream_t stream) {
  const float* query = (const float*)d_in[0];
  const float* key   = (const float*)d_in[1];
  const float* value = (const float*)d_in[2];
  const float* Wq = (const float*)d_in[3];
  const float* bq = (const float*)d_in[4];
  const float* Wk = (const float*)d_in[5];
  const float* bk = (const float*)d_in[6];
  const float* Wv = (const float*)d_in[7];
  const float* bv = (const float*)d_in[8];
  const float* Wo = (const float*)d_in[9];
  const float* bo = (const float*)d_in[10];
  float* out = (float*)d_out;

  char* ws = (char*)d_ws;
  size_t off = 0;
  auto alloc = [&](size_t bytes) { size_t o = off; off += (bytes + 255) & ~(size_t)255; return o; };
  float* alphas   = (float*)(ws + alloc(16));
  float* partials = (float*)(ws + alloc(4 * 256 * 4));
  float* vsum     = (float*)(ws + alloc(8 * 64 * 4));
  float* invs     = (float*)(ws + alloc(4 * 4096 * 4));
  unsigned short* wsq = (unsigned short*)(ws + alloc((size_t)1024 * 1024 * 2));
  unsigned short* wsk = (unsigned short*)(ws + alloc((size_t)256 * 1024 * 2));
  unsigned short* wsv = (unsigned short*)(ws + alloc((size_t)256 * 1024 * 2));
  unsigned short* wso = (unsigned short*)(ws + alloc((size_t)1024 * 1024 * 2));
  unsigned short* aq  = (unsigned short*)(ws + alloc((size_t)4096 * 1024 * 2)); // reused for ax
  unsigned short* akv = (unsigned short*)(ws + alloc((size_t)2 * 4096 * 1024 * 2)); // ak|av, reused as xbuf
  unsigned short* ak = akv;
  unsigned short* av = akv + (size_t)4096 * 1024;
  float* qbuf = (float*)(ws + alloc((size_t)4096 * 1024 * 4));
  float* kbuf = (float*)(ws + alloc((size_t)4096 * 256 * 4));
  float* vbuf = (float*)(ws + alloc((size_t)4096 * 256 * 4));
  float* xbuf = (float*)akv;   // 16MB overlay; ak/av dead after K/V GEMMs
  unsigned short* ax = aq;     // overlay; aq dead after Q GEMM

  absmean_stage1<<<dim3(256, 4), 256, 0, stream>>>(Wq, Wk, Wv, Wo, partials);
  absmean_stage2<<<4, 256, 0, stream>>>(partials, alphas);

  w_sign_bf16<<<1024, 256, 0, stream>>>(Wq, wsq);
  w_sign_bf16<<<256,  256, 0, stream>>>(Wk, wsk);
  w_sign_bf16<<<256,  256, 0, stream>>>(Wv, wsv);
  w_sign_bf16<<<1024, 256, 0, stream>>>(Wo, wso);

  act_quant<<<4096, 256, 0, stream>>>(query, aq, invs + 0 * 4096);
  act_quant<<<4096, 256, 0, stream>>>(key,   ak, invs + 1 * 4096);
  act_quant<<<4096, 256, 0, stream>>>(value, av, invs + 2 * 4096);

  gemm_bf16<<<dim3(32, 16), 256, 0, stream>>>(aq, wsq, bq, invs + 0 * 4096, alphas, 0, 1024, qbuf);
  gemm_bf16<<<dim3(32, 4),  256, 0, stream>>>(ak, wsk, bk, invs + 1 * 4096, alphas, 1, 256,  kbuf);
  gemm_bf16<<<dim3(32, 4),  256, 0, stream>>>(av, wsv, bv, invs + 2 * 4096, alphas, 2, 256,  vbuf);

  v_colsum<<<8, 256, 0, stream>>>(vbuf, vsum);

  attn_mfma<<<dim3(16, 32), 256, 0, stream>>>(qbuf, kbuf, vbuf, vsum, xbuf);

  act_quant<<<4096, 256, 0, stream>>>(xbuf, ax, invs + 3 * 4096);
  gemm_bf16<<<dim3(32, 16), 256, 0, stream>>>(ax, wso, bo, invs + 3 * 4096, alphas, 3, 1024, out);
}

// Round 3
// 291.348 us; speedup vs baseline: 17.7241x; 1.4837x over previous
//
#include <hip/hip_runtime.h>
#include <math.h>

typedef short bf16x8 __attribute__((ext_vector_type(8)));
typedef float f32x4 __attribute__((ext_vector_type(4)));

__device__ inline unsigned short f2bf_rtn(float x) {
  unsigned u = __float_as_uint(x);
  u += 0x7fffu + ((u >> 16) & 1u);
  return (unsigned short)(u >> 16);
}
__device__ inline unsigned short f2bf_trunc(float x) {  // exact for small-int-valued floats
  return (unsigned short)(__float_as_uint(x) >> 16);
}

// ---------------- weight abs-mean (two-stage, deterministic) ----------------
__global__ void absmean_stage1(const float* __restrict__ W0, const float* __restrict__ W1,
                               const float* __restrict__ W2, const float* __restrict__ W3,
                               float* __restrict__ partials) {
  int y = blockIdx.y;
  const float* W = (y == 0) ? W0 : (y == 1) ? W1 : (y == 2) ? W2 : W3;
  int n = (y == 0 || y == 3) ? (1024 * 1024) : (256 * 1024);
  int tid = threadIdx.x;
  float s = 0.f;
  for (int i = blockIdx.x * 256 + tid; i < n; i += 256 * 256) s += fabsf(W[i]);
  __shared__ float red[256];
  red[tid] = s; __syncthreads();
  for (int w = 128; w > 0; w >>= 1) { if (tid < w) red[tid] += red[tid + w]; __syncthreads(); }
  if (tid == 0) partials[y * 256 + blockIdx.x] = red[0];
}

__global__ void absmean_stage2(const float* __restrict__ partials, float* __restrict__ alphas) {
  int y = blockIdx.x; int tid = threadIdx.x;
  __shared__ float red[256];
  red[tid] = partials[y * 256 + tid]; __syncthreads();
  for (int w = 128; w > 0; w >>= 1) { if (tid < w) red[tid] += red[tid + w]; __syncthreads(); }
  int n = (y == 0 || y == 3) ? (1024 * 1024) : (256 * 1024);
  if (tid == 0) alphas[y] = red[0] / (float)n;
}

// ---------------- sign(W) -> bf16 (+1/-1/0), same [O][E] layout ----------------
__global__ void w_sign_bf16(const float* __restrict__ W, unsigned short* __restrict__ S) {
  int i = blockIdx.x * 256 + threadIdx.x;   // one float4 per thread
  float4 v = ((const float4*)W)[i];
  unsigned short s0 = (v.x > 0.f) ? 0x3F80 : (v.x < 0.f ? 0xBF80 : 0);
  unsigned short s1 = (v.y > 0.f) ? 0x3F80 : (v.y < 0.f ? 0xBF80 : 0);
  unsigned short s2 = (v.z > 0.f) ? 0x3F80 : (v.z < 0.f ? 0xBF80 : 0);
  unsigned short s3 = (v.w > 0.f) ? 0x3F80 : (v.w < 0.f ? 0xBF80 : 0);
  uint2 o;
  o.x = (unsigned)s0 | ((unsigned)s1 << 16);
  o.y = (unsigned)s2 | ((unsigned)s3 << 16);
  ((uint2*)S)[i] = o;
}

// ---------------- RMSNorm + activation quant -> bf16 ints + per-row dequant scale ----------------
__global__ void act_quant(const float* __restrict__ X, unsigned short* __restrict__ Q,
                          float* __restrict__ inv_s) {
  int r = blockIdx.x; int tid = threadIdx.x;
  const float* x = X + (size_t)r * 1024;
  float4 v = ((const float4*)x)[tid];
  float ss = v.x * v.x + v.y * v.y + v.z * v.z + v.w * v.w;
  float am = fmaxf(fmaxf(fabsf(v.x), fabsf(v.y)), fmaxf(fabsf(v.z), fabsf(v.w)));
  __shared__ float rs[256], rm[256];
  rs[tid] = ss; rm[tid] = am; __syncthreads();
  for (int w = 128; w > 0; w >>= 1) {
    if (tid < w) { rs[tid] += rs[tid + w]; rm[tid] = fmaxf(rm[tid], rm[tid + w]); }
    __syncthreads();
  }
  __shared__ float s_mul, s_inv;
  if (tid == 0) {
    float rms = sqrtf(rs[0] * (1.f / 1024.f) + 1e-6f);
    float inv_rms = 1.f / rms;
    float maxn = rm[0] * inv_rms * 0.03125f;          // max |x_norm|
    float cm = fmaxf(maxn, 1e-5f);
    float scale = 127.f / cm;
    s_mul = inv_rms * 0.03125f * scale;               // x -> x_norm*scale
    s_inv = cm / 127.f;                               // dequant factor
  }
  __syncthreads();
  float mul = s_mul;
  float q0 = fminf(fmaxf(rintf(v.x * mul), -128.f), 127.f);
  float q1 = fminf(fmaxf(rintf(v.y * mul), -128.f), 127.f);
  float q2 = fminf(fmaxf(rintf(v.z * mul), -128.f), 127.f);
  float q3 = fminf(fmaxf(rintf(v.w * mul), -128.f), 127.f);
  uint2 o;
  o.x = (unsigned)f2bf_trunc(q0) | ((unsigned)f2bf_trunc(q1) << 16);
  o.y = (unsigned)f2bf_trunc(q2) | ((unsigned)f2bf_trunc(q3) << 16);
  ((uint2*)(Q + (size_t)r * 1024))[tid] = o;
  if (tid == 0) inv_s[r] = s_inv;
}

// ---------------- bf16 MFMA bit-GEMM (exact: integer values in bf16) ----------------
// A [4096][1024] bf16 int-valued; Wb [N][1024] bf16 sign; out[r][o]=alpha*inv_s[r]*sum+bias[o]
__global__ __launch_bounds__(256) void gemm_bf16(
    const unsigned short* __restrict__ A, const unsigned short* __restrict__ Wb,
    const float* __restrict__ bias, const float* __restrict__ inv_s,
    const float* __restrict__ alphas, int aidx, int N, float* __restrict__ Out) {
  int lane = threadIdx.x & 63, wid = threadIdx.x >> 6;
  int rb = blockIdx.x * 128 + wid * 32;
  int cb = blockIdx.y * 64;
  int lm = lane & 15, lk = (lane >> 4) * 8;
  f32x4 zero = {0.f, 0.f, 0.f, 0.f};
  f32x4 acc[2][4];
  #pragma unroll
  for (int i = 0; i < 2; i++)
    #pragma unroll
    for (int j = 0; j < 4; j++) acc[i][j] = zero;
  const unsigned short* a0p = A + (size_t)(rb + lm) * 1024 + lk;
  const unsigned short* a1p = a0p + 16 * 1024;
  const unsigned short* b0p = Wb + (size_t)(cb + lm) * 1024 + lk;
  #pragma unroll 8
  for (int kk = 0; kk < 32; kk++) {
    bf16x8 a0 = *(const bf16x8*)(a0p + kk * 32);
    bf16x8 a1 = *(const bf16x8*)(a1p + kk * 32);
    #pragma unroll
    for (int ni = 0; ni < 4; ni++) {
      bf16x8 b = *(const bf16x8*)(b0p + (size_t)ni * 16 * 1024 + kk * 32);
      acc[0][ni] = __builtin_amdgcn_mfma_f32_16x16x32_bf16(a0, b, acc[0][ni], 0, 0, 0);
      acc[1][ni] = __builtin_amdgcn_mfma_f32_16x16x32_bf16(a1, b, acc[1][ni], 0, 0, 0);
    }
  }
  float al = alphas[aidx];
  int lh4 = (lane >> 4) * 4;
  #pragma unroll
  for (int mi = 0; mi < 2; mi++) {
    #pragma unroll
    for (int r = 0; r < 4; r++) {
      int row = rb + mi * 16 + lh4 + r;
      float f = al * inv_s[row];
      #pragma unroll
      for (int ni = 0; ni < 4; ni++) {
        int col = cb + ni * 16 + lm;
        Out[(size_t)row * N + col] = f * acc[mi][ni][r] + bias[col];
      }
    }
  }
}

// ---------------- V column sums per (b,g): two-stage, 256 blocks then 8 ----------------
__global__ void v_colsum1(const float* __restrict__ Vb, float* __restrict__ Vp) {
  int bg = blockIdx.x;              // 0..7
  int chunk = blockIdx.y;           // 0..31, each covers 64 t-rows
  int b = bg >> 2, g = bg & 3;
  int tid = threadIdx.x;            // 256
  int d = tid & 63, s = tid >> 6;   // 4 slices of 16 rows
  const float* base = Vb + (size_t)b * 2048 * 256 + g * 64 + d;
  int t0 = chunk * 64 + s * 16;
  float sum = 0.f;
  #pragma unroll 4
  for (int t = t0; t < t0 + 16; t++) sum += base[(size_t)t * 256];
  __shared__ float red[256];
  red[tid] = sum; __syncthreads();
  if (tid < 64) Vp[(bg * 32 + chunk) * 64 + d] = red[d] + red[64 + d] + red[128 + d] + red[192 + d];
}

__global__ void v_colsum2(const float* __restrict__ Vp, float* __restrict__ Vsum) {
  int bg = blockIdx.x;              // 0..7
  int d = threadIdx.x;              // 64
  float s = 0.f;
  #pragma unroll 8
  for (int c = 0; c < 32; c++) s += Vp[(bg * 32 + c) * 64 + d];
  Vsum[bg * 64 + d] = s;
}

// ---------------- GQA attention: bf16 MFMA flash-style with P=exp(s)-1 trick ----------------
#define APAD 72
__global__ __launch_bounds__(256) void attn_mfma(
    const float* __restrict__ Qb, const float* __restrict__ Kb, const float* __restrict__ Vb,
    const float* __restrict__ Vsum, float* __restrict__ Xb) {
  __shared__ __align__(16) unsigned short Kl[64 * APAD];
  __shared__ __align__(16) unsigned short Vt[64 * APAD];
  __shared__ __align__(16) unsigned short Pl[4 * 32 * APAD];
  int tid = threadIdx.x, lane = tid & 63, wid = tid >> 6;
  int bh = blockIdx.y; int b = bh >> 4, h = bh & 15, g = h >> 2;
  int qt0 = blockIdx.x * 128;
  int lm = lane & 15, lh = lane >> 4;

  // Q fragments (scale 0.125 folded in; exact pow2 multiply)
  bf16x8 qf[2][2];
  const float* qrow = Qb + (size_t)(b * 2048 + qt0 + wid * 32 + lm) * 1024 + h * 64 + lh * 8;
  #pragma unroll
  for (int mi = 0; mi < 2; mi++)
    #pragma unroll
    for (int kk = 0; kk < 2; kk++) {
      const float* p = qrow + mi * 16 * 1024 + kk * 32;
      float4 x0 = *(const float4*)p;
      float4 x1 = *(const float4*)(p + 4);
      union { bf16x8 v; unsigned short u[8]; } t;
      t.u[0] = f2bf_rtn(x0.x * 0.125f); t.u[1] = f2bf_rtn(x0.y * 0.125f);
      t.u[2] = f2bf_rtn(x0.z * 0.125f); t.u[3] = f2bf_rtn(x0.w * 0.125f);
      t.u[4] = f2bf_rtn(x1.x * 0.125f); t.u[5] = f2bf_rtn(x1.y * 0.125f);
      t.u[6] = f2bf_rtn(x1.z * 0.125f); t.u[7] = f2bf_rtn(x1.w * 0.125f);
      qf[mi][kk] = t.v;
    }

  f32x4 zero = {0.f, 0.f, 0.f, 0.f};
  f32x4 acc[2][4];
  #pragma unroll
  for (int i = 0; i < 2; i++)
    #pragma unroll
    for (int j = 0; j < 4; j++) acc[i][j] = zero;
  float rsum[2][4] = {{0.f,0.f,0.f,0.f},{0.f,0.f,0.f,0.f}};

  int st_t = tid >> 2, st_d = (tid & 3) * 16;
  unsigned short* pw = Pl + wid * 32 * APAD;

  for (int t0 = 0; t0 < 2048; t0 += 64) {
    __syncthreads();
    // ---- stage K (row-major) and V (transposed) as bf16 ----
    {
      const float* kp = Kb + (size_t)(b * 2048 + t0 + st_t) * 256 + g * 64 + st_d;
      const float* vp = Vb + (size_t)(b * 2048 + t0 + st_t) * 256 + g * 64 + st_d;
      float4 ka = *(const float4*)(kp);
      float4 kb = *(const float4*)(kp + 4);
      float4 kc = *(const float4*)(kp + 8);
      float4 kd = *(const float4*)(kp + 12);
      union { bf16x8 v; unsigned short u[8]; } kl0, kl1;
      kl0.u[0] = f2bf_rtn(ka.x); kl0.u[1] = f2bf_rtn(ka.y); kl0.u[2] = f2bf_rtn(ka.z); kl0.u[3] = f2bf_rtn(ka.w);
      kl0.u[4] = f2bf_rtn(kb.x); kl0.u[5] = f2bf_rtn(kb.y); kl0.u[6] = f2bf_rtn(kb.z); kl0.u[7] = f2bf_rtn(kb.w);
      kl1.u[0] = f2bf_rtn(kc.x); kl1.u[1] = f2bf_rtn(kc.y); kl1.u[2] = f2bf_rtn(kc.z); kl1.u[3] = f2bf_rtn(kc.w);
      kl1.u[4] = f2bf_rtn(kd.x); kl1.u[5] = f2bf_rtn(kd.y); kl1.u[6] = f2bf_rtn(kd.z); kl1.u[7] = f2bf_rtn(kd.w);
      *(bf16x8*)(&Kl[st_t * APAD + st_d]) = kl0.v;
      *(bf16x8*)(&Kl[st_t * APAD + st_d + 8]) = kl1.v;
      float4 va = *(const float4*)(vp);
      float4 vb = *(const float4*)(vp + 4);
      float4 vc = *(const float4*)(vp + 8);
      float4 vd = *(const float4*)(vp + 12);
      unsigned short vu[16];
      vu[0]=f2bf_rtn(va.x); vu[1]=f2bf_rtn(va.y); vu[2]=f2bf_rtn(va.z); vu[3]=f2bf_rtn(va.w);
      vu[4]=f2bf_rtn(vb.x); vu[5]=f2bf_rtn(vb.y); vu[6]=f2bf_rtn(vb.z); vu[7]=f2bf_rtn(vb.w);
      vu[8]=f2bf_rtn(vc.x); vu[9]=f2bf_rtn(vc.y); vu[10]=f2bf_rtn(vc.z); vu[11]=f2bf_rtn(vc.w);
      vu[12]=f2bf_rtn(vd.x); vu[13]=f2bf_rtn(vd.y); vu[14]=f2bf_rtn(vd.z); vu[15]=f2bf_rtn(vd.w);
      #pragma unroll
      for (int j = 0; j < 16; j++) Vt[(st_d + j) * APAD + st_t] = vu[j];
    }
    __syncthreads();

    // ---- S = Q K^T (16x16x32 MFMA) ----
    f32x4 s[2][4];
    #pragma unroll
    for (int i = 0; i < 2; i++)
      #pragma unroll
      for (int j = 0; j < 4; j++) s[i][j] = zero;
    #pragma unroll
    for (int kk = 0; kk < 2; kk++) {
      #pragma unroll
      for (int ni = 0; ni < 4; ni++) {
        bf16x8 kf = *(const bf16x8*)(&Kl[(ni * 16 + lm) * APAD + kk * 32 + lh * 8]);
        s[0][ni] = __builtin_amdgcn_mfma_f32_16x16x32_bf16(qf[0][kk], kf, s[0][ni], 0, 0, 0);
        s[1][ni] = __builtin_amdgcn_mfma_f32_16x16x32_bf16(qf[1][kk], kf, s[1][ni], 0, 0, 0);
      }
    }

    // ---- P~ = exp(s)-1 -> LDS (bf16), accumulate row sums in fp32 ----
    #pragma unroll
    for (int mi = 0; mi < 2; mi++)
      #pragma unroll
      for (int ni = 0; ni < 4; ni++)
        #pragma unroll
        for (int r = 0; r < 4; r++) {
          float pt = __expf(s[mi][ni][r]) - 1.0f;
          rsum[mi][r] += pt;
          pw[(mi * 16 + lh * 4 + r) * APAD + ni * 16 + lm] = f2bf_rtn(pt);
        }

    // ---- acc += P~ * V ----
    #pragma unroll
    for (int kk = 0; kk < 2; kk++) {
      bf16x8 pa0 = *(const bf16x8*)(pw + (lm) * APAD + kk * 32 + lh * 8);
      bf16x8 pa1 = *(const bf16x8*)(pw + (16 + lm) * APAD + kk * 32 + lh * 8);
      #pragma unroll
      for (int di = 0; di < 4; di++) {
        bf16x8 vf = *(const bf16x8*)(&Vt[(di * 16 + lm) * APAD + kk * 32 + lh * 8]);
        acc[0][di] = __builtin_amdgcn_mfma_f32_16x16x32_bf16(pa0, vf, acc[0][di], 0, 0, 0);
        acc[1][di] = __builtin_amdgcn_mfma_f32_16x16x32_bf16(pa1, vf, acc[1][di], 0, 0, 0);
      }
    }
  }

  // ---- epilogue: out = (acc + Vsum) / (2048 + rowsum) ----
  const float* vs = Vsum + (b * 4 + g) * 64;
  #pragma unroll
  for (int mi = 0; mi < 2; mi++) {
    #pragma unroll
    for (int r = 0; r < 4; r++) {
      float v = rsum[mi][r];
      v += __shfl_xor(v, 1); v += __shfl_xor(v, 2);
      v += __shfl_xor(v, 4); v += __shfl_xor(v, 8);
      float inv = 1.0f / (2048.0f + v);
      int row = qt0 + wid * 32 + mi * 16 + lh * 4 + r;
      float* op = Xb + (size_t)(b * 2048 + row) * 1024 + h * 64;
      #pragma unroll
      for (int di = 0; di < 4; di++)
        op[di * 16 + lm] = (acc[mi][di][r] + vs[di * 16 + lm]) * inv;
    }
  }
}

extern "C" void kernel_launch(void* const* d_in, const int* in_sizes, int n_in,
                              void* d_out, int out_size, void* d_ws, size_t ws_size,
                              hipStream_t stream) {
  const float* query = (const float*)d_in[0];
  const float* key   = (const float*)d_in[1];
  const float* value = (const float*)d_in[2];
  const float* Wq = (const float*)d_in[3];
  const float* bq = (const float*)d_in[4];
  const float* Wk = (const float*)d_in[5];
  const float* bk = (const float*)d_in[6];
  const float* Wv = (const float*)d_in[7];
  const float* bv = (const float*)d_in[8];
  const float* Wo = (const float*)d_in[9];
  const float* bo = (const float*)d_in[10];
  float* out = (float*)d_out;

  char* ws = (char*)d_ws;
  size_t off = 0;
  auto alloc = [&](size_t bytes) { size_t o = off; off += (bytes + 255) & ~(size_t)255; return o; };
  float* alphas   = (float*)(ws + alloc(16));
  float* partials = (float*)(ws + alloc(4 * 256 * 4));
  float* vsum     = (float*)(ws + alloc(8 * 64 * 4));
  float* vpart    = (float*)(ws + alloc(8 * 32 * 64 * 4));
  float* invs     = (float*)(ws + alloc(4 * 4096 * 4));
  unsigned short* wsq = (unsigned short*)(ws + alloc((size_t)1024 * 1024 * 2));
  unsigned short* wsk = (unsigned short*)(ws + alloc((size_t)256 * 1024 * 2));
  unsigned short* wsv = (unsigned short*)(ws + alloc((size_t)256 * 1024 * 2));
  unsigned short* wso = (unsigned short*)(ws + alloc((size_t)1024 * 1024 * 2));
  unsigned short* aq  = (unsigned short*)(ws + alloc((size_t)4096 * 1024 * 2)); // reused for ax
  unsigned short* akv = (unsigned short*)(ws + alloc((size_t)2 * 4096 * 1024 * 2)); // ak|av, reused as xbuf
  unsigned short* ak = akv;
  unsigned short* av = akv + (size_t)4096 * 1024;
  float* qbuf = (float*)(ws + alloc((size_t)4096 * 1024 * 4));
  float* kbuf = (float*)(ws + alloc((size_t)4096 * 256 * 4));
  float* vbuf = (float*)(ws + alloc((size_t)4096 * 256 * 4));
  float* xbuf = (float*)akv;   // 16MB overlay; ak/av dead after K/V GEMMs
  unsigned short* ax = aq;     // overlay; aq dead after Q GEMM

  absmean_stage1<<<dim3(256, 4), 256, 0, stream>>>(Wq, Wk, Wv, Wo, partials);
  absmean_stage2<<<4, 256, 0, stream>>>(partials, alphas);

  w_sign_bf16<<<1024, 256, 0, stream>>>(Wq, wsq);
  w_sign_bf16<<<256,  256, 0, stream>>>(Wk, wsk);
  w_sign_bf16<<<256,  256, 0, stream>>>(Wv, wsv);
  w_sign_bf16<<<1024, 256, 0, stream>>>(Wo, wso);

  act_quant<<<4096, 256, 0, stream>>>(query, aq, invs + 0 * 4096);
  act_quant<<<4096, 256, 0, stream>>>(key,   ak, invs + 1 * 4096);
  act_quant<<<4096, 256, 0, stream>>>(value, av, invs + 2 * 4096);

  gemm_bf16<<<dim3(32, 16), 256, 0, stream>>>(aq, wsq, bq, invs + 0 * 4096, alphas, 0, 1024, qbuf);
  gemm_bf16<<<dim3(32, 4),  256, 0, stream>>>(ak, wsk, bk, invs + 1 * 4096, alphas, 1, 256,  kbuf);
  gemm_bf16<<<dim3(32, 4),  256, 0, stream>>>(av, wsv, bv, invs + 2 * 4096, alphas, 2, 256,  vbuf);

  v_colsum1<<<dim3(8, 32), 256, 0, stream>>>(vbuf, vpart);
  v_colsum2<<<8, 64, 0, stream>>>(vpart, vsum);

  attn_mfma<<<dim3(16, 32), 256, 0, stream>>>(qbuf, kbuf, vbuf, vsum, xbuf);

  act_quant<<<4096, 256, 0, stream>>>(xbuf, ax, invs + 3 * 4096);
  gemm_bf16<<<dim3(32, 16), 256, 0, stream>>>(ax, wso, bo, invs + 3 * 4096, alphas, 3, 1024, out);
}

// Round 4
// 248.364 us; speedup vs baseline: 20.7915x; 1.1731x over previous
//
#include <hip/hip_runtime.h>
#include <math.h>

typedef short bf16x8 __attribute__((ext_vector_type(8)));
typedef float f32x4 __attribute__((ext_vector_type(4)));

__device__ inline unsigned short f2bf_rtn(float x) {
  unsigned u = __float_as_uint(x);
  u += 0x7fffu + ((u >> 16) & 1u);
  return (unsigned short)(u >> 16);
}
__device__ inline unsigned short f2bf_trunc(float x) {  // exact for small-int-valued floats
  return (unsigned short)(__float_as_uint(x) >> 16);
}

// ---------------- weight abs-mean (two-stage, deterministic) ----------------
__global__ void absmean_stage1(const float* __restrict__ W0, const float* __restrict__ W1,
                               const float* __restrict__ W2, const float* __restrict__ W3,
                               float* __restrict__ partials) {
  int y = blockIdx.y;
  const float* W = (y == 0) ? W0 : (y == 1) ? W1 : (y == 2) ? W2 : W3;
  int n = (y == 0 || y == 3) ? (1024 * 1024) : (256 * 1024);
  int tid = threadIdx.x;
  float s = 0.f;
  for (int i = blockIdx.x * 256 + tid; i < n; i += 256 * 256) s += fabsf(W[i]);
  __shared__ float red[256];
  red[tid] = s; __syncthreads();
  for (int w = 128; w > 0; w >>= 1) { if (tid < w) red[tid] += red[tid + w]; __syncthreads(); }
  if (tid == 0) partials[y * 256 + blockIdx.x] = red[0];
}

__global__ void absmean_stage2(const float* __restrict__ partials, float* __restrict__ alphas) {
  int y = blockIdx.x; int tid = threadIdx.x;
  __shared__ float red[256];
  red[tid] = partials[y * 256 + tid]; __syncthreads();
  for (int w = 128; w > 0; w >>= 1) { if (tid < w) red[tid] += red[tid + w]; __syncthreads(); }
  int n = (y == 0 || y == 3) ? (1024 * 1024) : (256 * 1024);
  if (tid == 0) alphas[y] = red[0] / (float)n;
}

// ---------------- sign(W) -> bf16 (+1/-1/0), all four weights, one launch ----------------
// outputs are contiguous: [wsq 1024*1024 | wsk 256*1024 | wsv 256*1024 | wso 1024*1024]
__global__ void w_sign4(const float* __restrict__ Wq, const float* __restrict__ Wk,
                        const float* __restrict__ Wv, const float* __restrict__ Wo,
                        unsigned short* __restrict__ out) {
  int i = blockIdx.x * 256 + threadIdx.x;   // float4 index, total 640K
  const float* W; int base;
  if (i < 262144)      { W = Wq; base = 0; }
  else if (i < 327680) { W = Wk; base = 262144; }
  else if (i < 393216) { W = Wv; base = 327680; }
  else                 { W = Wo; base = 393216; }
  float4 v = ((const float4*)W)[i - base];
  unsigned short s0 = (v.x > 0.f) ? 0x3F80 : (v.x < 0.f ? 0xBF80 : 0);
  unsigned short s1 = (v.y > 0.f) ? 0x3F80 : (v.y < 0.f ? 0xBF80 : 0);
  unsigned short s2 = (v.z > 0.f) ? 0x3F80 : (v.z < 0.f ? 0xBF80 : 0);
  unsigned short s3 = (v.w > 0.f) ? 0x3F80 : (v.w < 0.f ? 0xBF80 : 0);
  uint2 o;
  o.x = (unsigned)s0 | ((unsigned)s1 << 16);
  o.y = (unsigned)s2 | ((unsigned)s3 << 16);
  ((uint2*)out)[i] = o;
}

// ---------------- RMSNorm + act quant core (wave-shuffle reduction, 1 barrier) ----------------
__device__ inline void act_quant_body(const float* __restrict__ X, unsigned short* __restrict__ Q,
                                      float* __restrict__ inv_s, int r) {
  int tid = threadIdx.x, lane = tid & 63, wid = tid >> 6;
  const float* x = X + (size_t)r * 1024;
  float4 v = ((const float4*)x)[tid];
  float ss = v.x * v.x + v.y * v.y + v.z * v.z + v.w * v.w;
  float am = fmaxf(fmaxf(fabsf(v.x), fabsf(v.y)), fmaxf(fabsf(v.z), fabsf(v.w)));
  #pragma unroll
  for (int off = 32; off > 0; off >>= 1) {
    ss += __shfl_xor(ss, off);
    am = fmaxf(am, __shfl_xor(am, off));
  }
  __shared__ float rs[4], rm[4];
  if (lane == 0) { rs[wid] = ss; rm[wid] = am; }
  __syncthreads();
  ss = (rs[0] + rs[1]) + (rs[2] + rs[3]);
  am = fmaxf(fmaxf(rm[0], rm[1]), fmaxf(rm[2], rm[3]));
  float rms = sqrtf(ss * (1.f / 1024.f) + 1e-6f);
  float inv_rms = 1.f / rms;
  float maxn = am * inv_rms * 0.03125f;
  float cm = fmaxf(maxn, 1e-5f);
  float mul = inv_rms * 0.03125f * (127.f / cm);
  float q0 = fminf(fmaxf(rintf(v.x * mul), -128.f), 127.f);
  float q1 = fminf(fmaxf(rintf(v.y * mul), -128.f), 127.f);
  float q2 = fminf(fmaxf(rintf(v.z * mul), -128.f), 127.f);
  float q3 = fminf(fmaxf(rintf(v.w * mul), -128.f), 127.f);
  uint2 o;
  o.x = (unsigned)f2bf_trunc(q0) | ((unsigned)f2bf_trunc(q1) << 16);
  o.y = (unsigned)f2bf_trunc(q2) | ((unsigned)f2bf_trunc(q3) << 16);
  ((uint2*)(Q + (size_t)r * 1024))[tid] = o;
  if (tid == 0) inv_s[r] = cm / 127.f;
}

__global__ void act_quant3(const float* __restrict__ X0, const float* __restrict__ X1,
                           const float* __restrict__ X2, unsigned short* __restrict__ Q0,
                           unsigned short* __restrict__ Q1, unsigned short* __restrict__ Q2,
                           float* __restrict__ invs) {
  int which = blockIdx.y;
  const float* X = (which == 0) ? X0 : (which == 1) ? X1 : X2;
  unsigned short* Q = (which == 0) ? Q0 : (which == 1) ? Q1 : Q2;
  act_quant_body(X, Q, invs + which * 4096, blockIdx.x);
}

__global__ void act_quant1(const float* __restrict__ X, unsigned short* __restrict__ Q,
                           float* __restrict__ inv_s) {
  act_quant_body(X, Q, inv_s, blockIdx.x);
}

// ---------------- bf16 MFMA bit-GEMM (exact: integer values in bf16) ----------------
template <int N>
__device__ inline void gemm_body(const unsigned short* __restrict__ A,
                                 const unsigned short* __restrict__ Wb,
                                 const float* __restrict__ bias, const float* __restrict__ inv_s,
                                 float alpha, float* __restrict__ Out) {
  int lane = threadIdx.x & 63, wid = threadIdx.x >> 6;
  int rb = blockIdx.x * 128 + wid * 32;
  int cb = blockIdx.y * 64;
  int lm = lane & 15, lk = (lane >> 4) * 8;
  f32x4 zero = {0.f, 0.f, 0.f, 0.f};
  f32x4 acc[2][4];
  #pragma unroll
  for (int i = 0; i < 2; i++)
    #pragma unroll
    for (int j = 0; j < 4; j++) acc[i][j] = zero;
  const unsigned short* a0p = A + (size_t)(rb + lm) * 1024 + lk;
  const unsigned short* a1p = a0p + 16 * 1024;
  const unsigned short* b0p = Wb + (size_t)(cb + lm) * 1024 + lk;
  #pragma unroll 8
  for (int kk = 0; kk < 32; kk++) {
    bf16x8 a0 = *(const bf16x8*)(a0p + kk * 32);
    bf16x8 a1 = *(const bf16x8*)(a1p + kk * 32);
    #pragma unroll
    for (int ni = 0; ni < 4; ni++) {
      bf16x8 b = *(const bf16x8*)(b0p + (size_t)ni * 16 * 1024 + kk * 32);
      acc[0][ni] = __builtin_amdgcn_mfma_f32_16x16x32_bf16(a0, b, acc[0][ni], 0, 0, 0);
      acc[1][ni] = __builtin_amdgcn_mfma_f32_16x16x32_bf16(a1, b, acc[1][ni], 0, 0, 0);
    }
  }
  int lh4 = (lane >> 4) * 4;
  #pragma unroll
  for (int mi = 0; mi < 2; mi++) {
    #pragma unroll
    for (int r = 0; r < 4; r++) {
      int row = rb + mi * 16 + lh4 + r;
      float f = alpha * inv_s[row];
      #pragma unroll
      for (int ni = 0; ni < 4; ni++) {
        int col = cb + ni * 16 + lm;
        Out[(size_t)row * N + col] = f * acc[mi][ni][r] + bias[col];
      }
    }
  }
}

__global__ __launch_bounds__(256) void gemm_bf16_n1024(
    const unsigned short* __restrict__ A, const unsigned short* __restrict__ Wb,
    const float* __restrict__ bias, const float* __restrict__ inv_s,
    const float* __restrict__ alphas, int aidx, float* __restrict__ Out) {
  gemm_body<1024>(A, Wb, bias, inv_s, alphas[aidx], Out);
}

__global__ __launch_bounds__(256) void gemm_bf16_kv(
    const unsigned short* __restrict__ A0, const unsigned short* __restrict__ A1,
    const unsigned short* __restrict__ W0, const unsigned short* __restrict__ W1,
    const float* __restrict__ b0, const float* __restrict__ b1,
    const float* __restrict__ is0, const float* __restrict__ is1,
    const float* __restrict__ alphas, float* __restrict__ O0, float* __restrict__ O1) {
  if (blockIdx.z == 0) gemm_body<256>(A0, W0, b0, is0, alphas[1], O0);
  else                 gemm_body<256>(A1, W1, b1, is1, alphas[2], O1);
}

// ---------------- V column sums per (b,g): two-stage ----------------
__global__ void v_colsum1(const float* __restrict__ Vb, float* __restrict__ Vp) {
  int bg = blockIdx.x;              // 0..7
  int chunk = blockIdx.y;           // 0..31, each covers 64 t-rows
  int b = bg >> 2, g = bg & 3;
  int tid = threadIdx.x;            // 256
  int d = tid & 63, s = tid >> 6;   // 4 slices of 16 rows
  const float* base = Vb + (size_t)b * 2048 * 256 + g * 64 + d;
  int t0 = chunk * 64 + s * 16;
  float sum = 0.f;
  #pragma unroll 4
  for (int t = t0; t < t0 + 16; t++) sum += base[(size_t)t * 256];
  __shared__ float red[256];
  red[tid] = sum; __syncthreads();
  if (tid < 64) Vp[(bg * 32 + chunk) * 64 + d] = red[d] + red[64 + d] + red[128 + d] + red[192 + d];
}

__global__ void v_colsum2(const float* __restrict__ Vp, float* __restrict__ Vsum) {
  int bg = blockIdx.x;              // 0..7
  int d = threadIdx.x;              // 64
  float s = 0.f;
  #pragma unroll 8
  for (int c = 0; c < 32; c++) s += Vp[(bg * 32 + c) * 64 + d];
  Vsum[bg * 64 + d] = s;
}

// ---------------- GQA attention: bf16 MFMA, P=exp(s)-1, swizzled V^T, async staging ----------
#define APAD 72
__global__ __launch_bounds__(256) void attn_mfma(
    const float* __restrict__ Qb, const float* __restrict__ Kb, const float* __restrict__ Vb,
    const float* __restrict__ Vsum, float* __restrict__ Xb) {
  __shared__ __align__(16) unsigned short Kl[64 * APAD];   // [t][d] row-major
  __shared__ __align__(16) unsigned short Vt[64 * 64];     // [d][t], t-block XOR-swizzled
  __shared__ __align__(16) unsigned short Pl[4 * 32 * APAD];
  int tid = threadIdx.x, lane = tid & 63, wid = tid >> 6;
  int bh = blockIdx.y; int b = bh >> 4, h = bh & 15, g = h >> 2;
  int qt0 = blockIdx.x * 128;
  int lm = lane & 15, lh = lane >> 4;

  // Q fragments (scale 0.125 folded in; exact pow2 multiply)
  bf16x8 qf[2][2];
  const float* qrow = Qb + (size_t)(b * 2048 + qt0 + wid * 32 + lm) * 1024 + h * 64 + lh * 8;
  #pragma unroll
  for (int mi = 0; mi < 2; mi++)
    #pragma unroll
    for (int kk = 0; kk < 2; kk++) {
      const float* p = qrow + mi * 16 * 1024 + kk * 32;
      float4 x0 = *(const float4*)p;
      float4 x1 = *(const float4*)(p + 4);
      union { bf16x8 v; unsigned short u[8]; } t;
      t.u[0] = f2bf_rtn(x0.x * 0.125f); t.u[1] = f2bf_rtn(x0.y * 0.125f);
      t.u[2] = f2bf_rtn(x0.z * 0.125f); t.u[3] = f2bf_rtn(x0.w * 0.125f);
      t.u[4] = f2bf_rtn(x1.x * 0.125f); t.u[5] = f2bf_rtn(x1.y * 0.125f);
      t.u[6] = f2bf_rtn(x1.z * 0.125f); t.u[7] = f2bf_rtn(x1.w * 0.125f);
      qf[mi][kk] = t.v;
    }

  f32x4 zero = {0.f, 0.f, 0.f, 0.f};
  f32x4 acc[2][4];
  #pragma unroll
  for (int i = 0; i < 2; i++)
    #pragma unroll
    for (int j = 0; j < 4; j++) acc[i][j] = zero;
  float rsum[2][4] = {{0.f,0.f,0.f,0.f},{0.f,0.f,0.f,0.f}};

  int st_t = tid >> 2, st_d = (tid & 3) * 16;
  unsigned short* pw = Pl + wid * 32 * APAD;
  const float* kbase = Kb + (size_t)b * 2048 * 256 + g * 64 + st_d;
  const float* vbase = Vb + (size_t)b * 2048 * 256 + g * 64 + st_d;

  // prologue: load tile 0 into registers
  float4 kr[4], vr[4];
  {
    const float* kp = kbase + (size_t)st_t * 256;
    const float* vp = vbase + (size_t)st_t * 256;
    kr[0] = ((const float4*)kp)[0]; kr[1] = ((const float4*)kp)[1];
    kr[2] = ((const float4*)kp)[2]; kr[3] = ((const float4*)kp)[3];
    vr[0] = ((const float4*)vp)[0]; vr[1] = ((const float4*)vp)[1];
    vr[2] = ((const float4*)vp)[2]; vr[3] = ((const float4*)vp)[3];
  }

  for (int t0 = 0; t0 < 2048; t0 += 64) {
    __syncthreads();   // previous tile's LDS fully consumed
    // ---- convert regs -> LDS ----
    {
      union { bf16x8 v; unsigned short u[8]; } kl0, kl1;
      kl0.u[0] = f2bf_rtn(kr[0].x); kl0.u[1] = f2bf_rtn(kr[0].y); kl0.u[2] = f2bf_rtn(kr[0].z); kl0.u[3] = f2bf_rtn(kr[0].w);
      kl0.u[4] = f2bf_rtn(kr[1].x); kl0.u[5] = f2bf_rtn(kr[1].y); kl0.u[6] = f2bf_rtn(kr[1].z); kl0.u[7] = f2bf_rtn(kr[1].w);
      kl1.u[0] = f2bf_rtn(kr[2].x); kl1.u[1] = f2bf_rtn(kr[2].y); kl1.u[2] = f2bf_rtn(kr[2].z); kl1.u[3] = f2bf_rtn(kr[2].w);
      kl1.u[4] = f2bf_rtn(kr[3].x); kl1.u[5] = f2bf_rtn(kr[3].y); kl1.u[6] = f2bf_rtn(kr[3].z); kl1.u[7] = f2bf_rtn(kr[3].w);
      *(bf16x8*)(&Kl[st_t * APAD + st_d]) = kl0.v;
      *(bf16x8*)(&Kl[st_t * APAD + st_d + 8]) = kl1.v;
      unsigned short vu[16];
      vu[0]=f2bf_rtn(vr[0].x); vu[1]=f2bf_rtn(vr[0].y); vu[2]=f2bf_rtn(vr[0].z); vu[3]=f2bf_rtn(vr[0].w);
      vu[4]=f2bf_rtn(vr[1].x); vu[5]=f2bf_rtn(vr[1].y); vu[6]=f2bf_rtn(vr[1].z); vu[7]=f2bf_rtn(vr[1].w);
      vu[8]=f2bf_rtn(vr[2].x); vu[9]=f2bf_rtn(vr[2].y); vu[10]=f2bf_rtn(vr[2].z); vu[11]=f2bf_rtn(vr[2].w);
      vu[12]=f2bf_rtn(vr[3].x); vu[13]=f2bf_rtn(vr[3].y); vu[14]=f2bf_rtn(vr[3].z); vu[15]=f2bf_rtn(vr[3].w);
      #pragma unroll
      for (int j = 0; j < 16; j++) {
        int d = st_d + j;
        int blk = (st_t >> 3) ^ ((d >> 3) & 7);
        Vt[d * 64 + (blk << 3) + (st_t & 7)] = vu[j];
      }
    }
    __syncthreads();
    // ---- issue next tile's global loads (latency hides under compute) ----
    if (t0 + 64 < 2048) {
      const float* kp = kbase + (size_t)(t0 + 64 + st_t) * 256;
      const float* vp = vbase + (size_t)(t0 + 64 + st_t) * 256;
      kr[0] = ((const float4*)kp)[0]; kr[1] = ((const float4*)kp)[1];
      kr[2] = ((const float4*)kp)[2]; kr[3] = ((const float4*)kp)[3];
      vr[0] = ((const float4*)vp)[0]; vr[1] = ((const float4*)vp)[1];
      vr[2] = ((const float4*)vp)[2]; vr[3] = ((const float4*)vp)[3];
    }

    // ---- S = Q K^T ----
    f32x4 s[2][4];
    #pragma unroll
    for (int i = 0; i < 2; i++)
      #pragma unroll
      for (int j = 0; j < 4; j++) s[i][j] = zero;
    #pragma unroll
    for (int kk = 0; kk < 2; kk++) {
      #pragma unroll
      for (int ni = 0; ni < 4; ni++) {
        bf16x8 kf = *(const bf16x8*)(&Kl[(ni * 16 + lm) * APAD + kk * 32 + lh * 8]);
        s[0][ni] = __builtin_amdgcn_mfma_f32_16x16x32_bf16(qf[0][kk], kf, s[0][ni], 0, 0, 0);
        s[1][ni] = __builtin_amdgcn_mfma_f32_16x16x32_bf16(qf[1][kk], kf, s[1][ni], 0, 0, 0);
      }
    }

    // ---- P~ = exp(s)-1 -> per-wave LDS (bf16), fp32 row sums ----
    #pragma unroll
    for (int mi = 0; mi < 2; mi++)
      #pragma unroll
      for (int ni = 0; ni < 4; ni++)
        #pragma unroll
        for (int r = 0; r < 4; r++) {
          float pt = __expf(s[mi][ni][r]) - 1.0f;
          rsum[mi][r] += pt;
          pw[(mi * 16 + lh * 4 + r) * APAD + ni * 16 + lm] = f2bf_rtn(pt);
        }

    // ---- acc += P~ * V  (V read via swizzled b128) ----
    #pragma unroll
    for (int kk = 0; kk < 2; kk++) {
      bf16x8 pa0 = *(const bf16x8*)(pw + (lm) * APAD + kk * 32 + lh * 8);
      bf16x8 pa1 = *(const bf16x8*)(pw + (16 + lm) * APAD + kk * 32 + lh * 8);
      #pragma unroll
      for (int di = 0; di < 4; di++) {
        int row = di * 16 + lm;
        int blk = ((kk * 4 + lh) ^ ((row >> 3) & 7)) << 3;
        bf16x8 vf = *(const bf16x8*)(&Vt[row * 64 + blk]);
        acc[0][di] = __builtin_amdgcn_mfma_f32_16x16x32_bf16(pa0, vf, acc[0][di], 0, 0, 0);
        acc[1][di] = __builtin_amdgcn_mfma_f32_16x16x32_bf16(pa1, vf, acc[1][di], 0, 0, 0);
      }
    }
  }

  // ---- epilogue: out = (acc + Vsum) / (2048 + rowsum) ----
  const float* vs = Vsum + (b * 4 + g) * 64;
  #pragma unroll
  for (int mi = 0; mi < 2; mi++) {
    #pragma unroll
    for (int r = 0; r < 4; r++) {
      float v = rsum[mi][r];
      v += __shfl_xor(v, 1); v += __shfl_xor(v, 2);
      v += __shfl_xor(v, 4); v += __shfl_xor(v, 8);
      float inv = 1.0f / (2048.0f + v);
      int row = qt0 + wid * 32 + mi * 16 + lh * 4 + r;
      float* op = Xb + (size_t)(b * 2048 + row) * 1024 + h * 64;
      #pragma unroll
      for (int di = 0; di < 4; di++)
        op[di * 16 + lm] = (acc[mi][di][r] + vs[di * 16 + lm]) * inv;
    }
  }
}

extern "C" void kernel_launch(void* const* d_in, const int* in_sizes, int n_in,
                              void* d_out, int out_size, void* d_ws, size_t ws_size,
                              hipStream_t stream) {
  const float* query = (const float*)d_in[0];
  const float* key   = (const float*)d_in[1];
  const float* value = (const float*)d_in[2];
  const float* Wq = (const float*)d_in[3];
  const float* bq = (const float*)d_in[4];
  const float* Wk = (const float*)d_in[5];
  const float* bk = (const float*)d_in[6];
  const float* Wv = (const float*)d_in[7];
  const float* bv = (const float*)d_in[8];
  const float* Wo = (const float*)d_in[9];
  const float* bo = (const float*)d_in[10];
  float* out = (float*)d_out;

  char* ws = (char*)d_ws;
  size_t off = 0;
  auto alloc = [&](size_t bytes) { size_t o = off; off += (bytes + 255) & ~(size_t)255; return o; };
  float* alphas   = (float*)(ws + alloc(16));
  float* partials = (float*)(ws + alloc(4 * 256 * 4));
  float* vsum     = (float*)(ws + alloc(8 * 64 * 4));
  float* vpart    = (float*)(ws + alloc(8 * 32 * 64 * 4));
  float* invs     = (float*)(ws + alloc(4 * 4096 * 4));
  // NOTE: the four sign-weight buffers must stay contiguous in this order (w_sign4 writes flat)
  unsigned short* wsq = (unsigned short*)(ws + alloc((size_t)1024 * 1024 * 2));
  unsigned short* wsk = (unsigned short*)(ws + alloc((size_t)256 * 1024 * 2));
  unsigned short* wsv = (unsigned short*)(ws + alloc((size_t)256 * 1024 * 2));
  unsigned short* wso = (unsigned short*)(ws + alloc((size_t)1024 * 1024 * 2));
  unsigned short* aq  = (unsigned short*)(ws + alloc((size_t)4096 * 1024 * 2)); // reused for ax
  unsigned short* akv = (unsigned short*)(ws + alloc((size_t)2 * 4096 * 1024 * 2)); // ak|av, reused as xbuf
  unsigned short* ak = akv;
  unsigned short* av = akv + (size_t)4096 * 1024;
  float* qbuf = (float*)(ws + alloc((size_t)4096 * 1024 * 4));
  float* kbuf = (float*)(ws + alloc((size_t)4096 * 256 * 4));
  float* vbuf = (float*)(ws + alloc((size_t)4096 * 256 * 4));
  float* xbuf = (float*)akv;   // 16MB overlay; ak/av dead after K/V GEMMs
  unsigned short* ax = aq;     // overlay; aq dead after Q GEMM

  absmean_stage1<<<dim3(256, 4), 256, 0, stream>>>(Wq, Wk, Wv, Wo, partials);
  absmean_stage2<<<4, 256, 0, stream>>>(partials, alphas);

  w_sign4<<<2560, 256, 0, stream>>>(Wq, Wk, Wv, Wo, wsq);

  act_quant3<<<dim3(4096, 3), 256, 0, stream>>>(query, key, value, aq, ak, av, invs);

  gemm_bf16_n1024<<<dim3(32, 16), 256, 0, stream>>>(aq, wsq, bq, invs + 0 * 4096, alphas, 0, qbuf);
  gemm_bf16_kv<<<dim3(32, 4, 2), 256, 0, stream>>>(ak, av, wsk, wsv, bk, bv,
                                                   invs + 1 * 4096, invs + 2 * 4096,
                                                   alphas, kbuf, vbuf);

  v_colsum1<<<dim3(8, 32), 256, 0, stream>>>(vbuf, vpart);
  v_colsum2<<<8, 64, 0, stream>>>(vpart, vsum);

  attn_mfma<<<dim3(16, 32), 256, 0, stream>>>(qbuf, kbuf, vbuf, vsum, xbuf);

  act_quant1<<<4096, 256, 0, stream>>>(xbuf, ax, invs + 3 * 4096);
  gemm_bf16_n1024<<<dim3(32, 16), 256, 0, stream>>>(ax, wso, bo, invs + 3 * 4096, alphas, 3, out);
}

// Round 5
// 223.515 us; speedup vs baseline: 23.1030x; 1.1112x over previous
//
#include <hip/hip_runtime.h>
#include <hip/hip_bf16.h>
#include <math.h>

typedef short bf16x8 __attribute__((ext_vector_type(8)));
typedef float f32x4 __attribute__((ext_vector_type(4)));

__device__ inline unsigned short f2bf(float x) {          // RNE
  __hip_bfloat16 h = __float2bfloat16(x);
  return *reinterpret_cast<unsigned short*>(&h);
}
__device__ inline unsigned f2bf2(float lo, float hi) {
  unsigned a = f2bf(lo), b = f2bf(hi);
  return a | (b << 16);
}
__device__ inline float bf2f(unsigned short u) {
  return __uint_as_float(((unsigned)u) << 16);
}
__device__ inline unsigned short f2bf_trunc(float x) {    // exact for small ints
  return (unsigned short)(__float_as_uint(x) >> 16);
}

// ---------------- weight abs-mean (two-stage, deterministic) ----------------
__global__ void absmean_stage1(const float* __restrict__ W0, const float* __restrict__ W1,
                               const float* __restrict__ W2, const float* __restrict__ W3,
                               float* __restrict__ partials) {
  int y = blockIdx.y;
  const float* W = (y == 0) ? W0 : (y == 1) ? W1 : (y == 2) ? W2 : W3;
  int n = (y == 0 || y == 3) ? (1024 * 1024) : (256 * 1024);
  int tid = threadIdx.x;
  float s = 0.f;
  for (int i = blockIdx.x * 256 + tid; i < n; i += 256 * 256) s += fabsf(W[i]);
  __shared__ float red[256];
  red[tid] = s; __syncthreads();
  for (int w = 128; w > 0; w >>= 1) { if (tid < w) red[tid] += red[tid + w]; __syncthreads(); }
  if (tid == 0) partials[y * 256 + blockIdx.x] = red[0];
}

__global__ void absmean_stage2(const float* __restrict__ partials, float* __restrict__ alphas) {
  int y = blockIdx.x; int tid = threadIdx.x;
  __shared__ float red[256];
  red[tid] = partials[y * 256 + tid]; __syncthreads();
  for (int w = 128; w > 0; w >>= 1) { if (tid < w) red[tid] += red[tid + w]; __syncthreads(); }
  int n = (y == 0 || y == 3) ? (1024 * 1024) : (256 * 1024);
  if (tid == 0) alphas[y] = red[0] / (float)n;
}

// ---------------- sign(W) -> bf16, all four weights, one launch ----------------
__global__ void w_sign4(const float* __restrict__ Wq, const float* __restrict__ Wk,
                        const float* __restrict__ Wv, const float* __restrict__ Wo,
                        unsigned short* __restrict__ out) {
  int i = blockIdx.x * 256 + threadIdx.x;
  const float* W; int base;
  if (i < 262144)      { W = Wq; base = 0; }
  else if (i < 327680) { W = Wk; base = 262144; }
  else if (i < 393216) { W = Wv; base = 327680; }
  else                 { W = Wo; base = 393216; }
  float4 v = ((const float4*)W)[i - base];
  unsigned short s0 = (v.x > 0.f) ? 0x3F80 : (v.x < 0.f ? 0xBF80 : 0);
  unsigned short s1 = (v.y > 0.f) ? 0x3F80 : (v.y < 0.f ? 0xBF80 : 0);
  unsigned short s2 = (v.z > 0.f) ? 0x3F80 : (v.z < 0.f ? 0xBF80 : 0);
  unsigned short s3 = (v.w > 0.f) ? 0x3F80 : (v.w < 0.f ? 0xBF80 : 0);
  uint2 o;
  o.x = (unsigned)s0 | ((unsigned)s1 << 16);
  o.y = (unsigned)s2 | ((unsigned)s3 << 16);
  ((uint2*)out)[i] = o;
}

// ---------------- RMSNorm + act quant (wave-shuffle, 1 barrier) ----------------
__device__ inline void act_quant_body(const float* __restrict__ X, unsigned short* __restrict__ Q,
                                      float* __restrict__ inv_s, int r) {
  int tid = threadIdx.x, lane = tid & 63, wid = tid >> 6;
  const float* x = X + (size_t)r * 1024;
  float4 v = ((const float4*)x)[tid];
  float ss = v.x * v.x + v.y * v.y + v.z * v.z + v.w * v.w;
  float am = fmaxf(fmaxf(fabsf(v.x), fabsf(v.y)), fmaxf(fabsf(v.z), fabsf(v.w)));
  #pragma unroll
  for (int off = 32; off > 0; off >>= 1) {
    ss += __shfl_xor(ss, off);
    am = fmaxf(am, __shfl_xor(am, off));
  }
  __shared__ float rs[4], rm[4];
  if (lane == 0) { rs[wid] = ss; rm[wid] = am; }
  __syncthreads();
  ss = (rs[0] + rs[1]) + (rs[2] + rs[3]);
  am = fmaxf(fmaxf(rm[0], rm[1]), fmaxf(rm[2], rm[3]));
  float rms = sqrtf(ss * (1.f / 1024.f) + 1e-6f);
  float inv_rms = 1.f / rms;
  float maxn = am * inv_rms * 0.03125f;
  float cm = fmaxf(maxn, 1e-5f);
  float mul = inv_rms * 0.03125f * (127.f / cm);
  float q0 = fminf(fmaxf(rintf(v.x * mul), -128.f), 127.f);
  float q1 = fminf(fmaxf(rintf(v.y * mul), -128.f), 127.f);
  float q2 = fminf(fmaxf(rintf(v.z * mul), -128.f), 127.f);
  float q3 = fminf(fmaxf(rintf(v.w * mul), -128.f), 127.f);
  uint2 o;
  o.x = (unsigned)f2bf_trunc(q0) | ((unsigned)f2bf_trunc(q1) << 16);
  o.y = (unsigned)f2bf_trunc(q2) | ((unsigned)f2bf_trunc(q3) << 16);
  ((uint2*)(Q + (size_t)r * 1024))[tid] = o;
  if (tid == 0) inv_s[r] = cm / 127.f;
}

__global__ void act_quant3(const float* __restrict__ X0, const float* __restrict__ X1,
                           const float* __restrict__ X2, unsigned short* __restrict__ Q0,
                           unsigned short* __restrict__ Q1, unsigned short* __restrict__ Q2,
                           float* __restrict__ invs) {
  int which = blockIdx.y;
  const float* X = (which == 0) ? X0 : (which == 1) ? X1 : X2;
  unsigned short* Q = (which == 0) ? Q0 : (which == 1) ? Q1 : Q2;
  act_quant_body(X, Q, invs + which * 4096, blockIdx.x);
}

__global__ void act_quant1(const float* __restrict__ X, unsigned short* __restrict__ Q,
                           float* __restrict__ inv_s) {
  act_quant_body(X, Q, inv_s, blockIdx.x);
}

// ---------------- bf16 MFMA bit-GEMM core with epilogue policy ----------------
// EPI: 0 = fp32 [row][N]; 1 = bf16 [row][1024] scaled by 0.125 (Q for attn);
//      2 = bf16 K layout [b*4+g][t][64]; 3 = bf16 V^T layout [b*4+g][d][2048]
template <int N, int EPI>
__device__ inline void gemm_body(const unsigned short* __restrict__ A,
                                 const unsigned short* __restrict__ Wb,
                                 const float* __restrict__ bias, const float* __restrict__ inv_s,
                                 float alpha, void* __restrict__ Outv) {
  int lane = threadIdx.x & 63, wid = threadIdx.x >> 6;
  int rb = blockIdx.x * 128 + wid * 32;
  int cb = blockIdx.y * 64;
  int lm = lane & 15, lk = (lane >> 4) * 8;
  f32x4 zero = {0.f, 0.f, 0.f, 0.f};
  f32x4 acc[2][4];
  #pragma unroll
  for (int i = 0; i < 2; i++)
    #pragma unroll
    for (int j = 0; j < 4; j++) acc[i][j] = zero;
  const unsigned short* a0p = A + (size_t)(rb + lm) * 1024 + lk;
  const unsigned short* a1p = a0p + 16 * 1024;
  const unsigned short* b0p = Wb + (size_t)(cb + lm) * 1024 + lk;
  #pragma unroll 8
  for (int kk = 0; kk < 32; kk++) {
    bf16x8 a0 = *(const bf16x8*)(a0p + kk * 32);
    bf16x8 a1 = *(const bf16x8*)(a1p + kk * 32);
    #pragma unroll
    for (int ni = 0; ni < 4; ni++) {
      bf16x8 b = *(const bf16x8*)(b0p + (size_t)ni * 16 * 1024 + kk * 32);
      acc[0][ni] = __builtin_amdgcn_mfma_f32_16x16x32_bf16(a0, b, acc[0][ni], 0, 0, 0);
      acc[1][ni] = __builtin_amdgcn_mfma_f32_16x16x32_bf16(a1, b, acc[1][ni], 0, 0, 0);
    }
  }
  int lh4 = (lane >> 4) * 4;
  #pragma unroll
  for (int mi = 0; mi < 2; mi++) {
    #pragma unroll
    for (int r = 0; r < 4; r++) {
      int row = rb + mi * 16 + lh4 + r;
      float f = alpha * inv_s[row];
      #pragma unroll
      for (int ni = 0; ni < 4; ni++) {
        int col = cb + ni * 16 + lm;
        float val = f * acc[mi][ni][r] + bias[col];
        if (EPI == 0) {
          ((float*)Outv)[(size_t)row * N + col] = val;
        } else if (EPI == 1) {
          ((unsigned short*)Outv)[(size_t)row * 1024 + col] = f2bf(val * 0.125f);
        } else if (EPI == 2) {
          int b = row >> 11, t = row & 2047, g = col >> 6, d = col & 63;
          ((unsigned short*)Outv)[(((size_t)(b * 4 + g)) << 17) + t * 64 + d] = f2bf(val);
        } else {
          int b = row >> 11, t = row & 2047, g = col >> 6, d = col & 63;
          ((unsigned short*)Outv)[(((size_t)(b * 4 + g)) << 17) + (size_t)d * 2048 + t] = f2bf(val);
        }
      }
    }
  }
}

__global__ __launch_bounds__(256) void gemm_q(
    const unsigned short* __restrict__ A, const unsigned short* __restrict__ Wb,
    const float* __restrict__ bias, const float* __restrict__ inv_s,
    const float* __restrict__ alphas, unsigned short* __restrict__ Out) {
  gemm_body<1024, 1>(A, Wb, bias, inv_s, alphas[0], Out);
}

__global__ __launch_bounds__(256) void gemm_kv(
    const unsigned short* __restrict__ A0, const unsigned short* __restrict__ A1,
    const unsigned short* __restrict__ W0, const unsigned short* __restrict__ W1,
    const float* __restrict__ b0, const float* __restrict__ b1,
    const float* __restrict__ is0, const float* __restrict__ is1,
    const float* __restrict__ alphas, unsigned short* __restrict__ K16,
    unsigned short* __restrict__ V16T) {
  if (blockIdx.z == 0) gemm_body<256, 2>(A0, W0, b0, is0, alphas[1], K16);
  else                 gemm_body<256, 3>(A1, W1, b1, is1, alphas[2], V16T);
}

__global__ __launch_bounds__(256) void gemm_o(
    const unsigned short* __restrict__ A, const unsigned short* __restrict__ Wb,
    const float* __restrict__ bias, const float* __restrict__ inv_s,
    const float* __restrict__ alphas, float* __restrict__ Out) {
  gemm_body<1024, 0>(A, Wb, bias, inv_s, alphas[3], Out);
}

// ---------------- V column sums from V^T bf16 (contiguous rows) ----------------
__global__ void v_colsum_b(const unsigned short* __restrict__ VT, float* __restrict__ Vsum) {
  int row = blockIdx.x * 4 + (threadIdx.x >> 6);   // 0..511 = bg*64 + d
  int lane = threadIdx.x & 63;
  const unsigned short* p = VT + (size_t)row * 2048 + lane * 8;
  float s = 0.f;
  #pragma unroll
  for (int i = 0; i < 4; i++) {
    uint4 v = *(const uint4*)(p + i * 512);
    s += bf2f((unsigned short)(v.x)) + bf2f((unsigned short)(v.x >> 16));
    s += bf2f((unsigned short)(v.y)) + bf2f((unsigned short)(v.y >> 16));
    s += bf2f((unsigned short)(v.z)) + bf2f((unsigned short)(v.z >> 16));
    s += bf2f((unsigned short)(v.w)) + bf2f((unsigned short)(v.w >> 16));
  }
  #pragma unroll
  for (int off = 32; off > 0; off >>= 1) s += __shfl_xor(s, off);
  if (lane == 0) Vsum[row] = s;
}

// ---------------- GQA attention: swapped QK^T, register-resident P~ ------------
// 512 threads = 8 waves; wave owns 16 q-rows. LDS: Kl[t][64], Vt[d][64], both with
// 16B-block XOR swizzle: phys_blk = logical_blk ^ (row&7)  (conflict-free per-8-lane).
__global__ __launch_bounds__(512, 4) void attn_mfma(
    const unsigned short* __restrict__ Qb, const unsigned short* __restrict__ Kb,
    const unsigned short* __restrict__ Vb, const float* __restrict__ Vsum,
    float* __restrict__ Xb) {
  __shared__ __align__(16) unsigned short Kl[64 * 64];
  __shared__ __align__(16) unsigned short Vt[64 * 64];
  int tid = threadIdx.x, lane = tid & 63, wid = tid >> 6;
  int bh = blockIdx.y; int b = bh >> 4, h = bh & 15, g = h >> 2;
  int qt0 = blockIdx.x * 128;
  int lm = lane & 15, lh = lane >> 4;
  int m7 = lm & 7, h1 = lh >> 1, h0 = lh & 1;

  // Q fragments (qb16 already scaled by 0.125): B-operand, row=q=lm, k=d
  bf16x8 qf[2];
  {
    const unsigned short* qp = Qb + (size_t)(b * 2048 + qt0 + wid * 16 + lm) * 1024 + h * 64 + lh * 8;
    qf[0] = *(const bf16x8*)(qp);
    qf[1] = *(const bf16x8*)(qp + 32);
  }

  f32x4 zero = {0.f, 0.f, 0.f, 0.f};
  f32x4 acc[4];
  #pragma unroll
  for (int i = 0; i < 4; i++) acc[i] = zero;
  float rsum = 0.f;   // partial row-sum for q = lm (this lane's 16 t's per tile)

  // staging: thread stages one 16B block of K and one of V per tile
  int s_t = tid >> 3;           // K: t-row / V: d-row  (0..63)
  int s_u = tid & 7;            // phys block slot
  int s_swz = (s_u ^ (s_t & 7)) << 3;    // logical block -> element offset
  const unsigned short* kg = Kb + (((size_t)(b * 4 + g)) << 17) + s_t * 64 + s_swz;
  const unsigned short* vg = Vb + (((size_t)(b * 4 + g)) << 17) + (size_t)s_t * 2048 + s_swz;
  unsigned short* kd = &Kl[s_t * 64 + s_u * 8];
  unsigned short* vd = &Vt[s_t * 64 + s_u * 8];

  // K-frag read offsets (shorts): t = ti*16+lm, logical d-blk = kk*4+lh
  const bf16x8* kfp0 = (const bf16x8*)&Kl[lm * 64 + (((0 + lh) ^ m7) << 3)];
  const bf16x8* kfp1 = (const bf16x8*)&Kl[lm * 64 + (((4 + lh) ^ m7) << 3)];
  // V-frag read offsets: d = di*16+lm, t0 = 32kk+16s+4lh -> blk = (4kk+2s+h1)^m7, +4*h0 shorts
  int vo00 = lm * 64 + (((0 + h1) ^ m7) << 3) + h0 * 4;
  int vo01 = lm * 64 + (((2 + h1) ^ m7) << 3) + h0 * 4;
  int vo10 = lm * 64 + (((4 + h1) ^ m7) << 3) + h0 * 4;
  int vo11 = lm * 64 + (((6 + h1) ^ m7) << 3) + h0 * 4;

  // prologue: prefetch tile 0
  uint4 kr = *(const uint4*)kg;
  uint4 vr = *(const uint4*)vg;
  kg += 4096; vg += 64;

  for (int t0 = 0; t0 < 2048; t0 += 64) {
    __syncthreads();                 // previous tile fully consumed
    *(uint4*)kd = kr;
    *(uint4*)vd = vr;
    __syncthreads();
    if (t0 + 64 < 2048) {            // prefetch next tile (hides under compute)
      kr = *(const uint4*)kg;
      vr = *(const uint4*)vg;
      kg += 4096; vg += 64;
    }

    // ---- swapped QK^T: s = mfma(K, Q): D rows = t (4lh+r), cols = q (lm) ----
    f32x4 sv[4];
    #pragma unroll
    for (int ti = 0; ti < 4; ti++) {
      bf16x8 k0 = kfp0[ti * 128];    // +ti*1024 shorts
      bf16x8 k1 = kfp1[ti * 128];
      f32x4 z = zero;
      z = __builtin_amdgcn_mfma_f32_16x16x32_bf16(k0, qf[0], z, 0, 0, 0);
      z = __builtin_amdgcn_mfma_f32_16x16x32_bf16(k1, qf[1], z, 0, 0, 0);
      sv[ti] = z;
    }

    // ---- P~ = exp(s)-1 in registers; pack to bf16 pairs ----
    unsigned pk[4][2];
    #pragma unroll
    for (int ti = 0; ti < 4; ti++) {
      float p0 = __expf(sv[ti][0]) - 1.f;
      float p1 = __expf(sv[ti][1]) - 1.f;
      float p2 = __expf(sv[ti][2]) - 1.f;
      float p3 = __expf(sv[ti][3]) - 1.f;
      rsum += (p0 + p1) + (p2 + p3);
      pk[ti][0] = f2bf2(p0, p1);
      pk[ti][1] = f2bf2(p2, p3);
    }

    // ---- PV: A-frag = own P~ (k-order: t = 32kk+4lh+{0..3} then +16) ----
    #pragma unroll
    for (int kk = 0; kk < 2; kk++) {
      union { bf16x8 v; unsigned u[4]; } pf;
      pf.u[0] = pk[2 * kk][0];     pf.u[1] = pk[2 * kk][1];
      pf.u[2] = pk[2 * kk + 1][0]; pf.u[3] = pk[2 * kk + 1][1];
      int va = kk ? vo10 : vo00, vb2 = kk ? vo11 : vo01;
      #pragma unroll
      for (int di = 0; di < 4; di++) {
        union { bf16x8 v; uint2 q[2]; } vf;
        vf.q[0] = *(const uint2*)&Vt[va + di * 1024];
        vf.q[1] = *(const uint2*)&Vt[vb2 + di * 1024];
        acc[di] = __builtin_amdgcn_mfma_f32_16x16x32_bf16(pf.v, vf.v, acc[di], 0, 0, 0);
      }
    }
  }

  // ---- epilogue: out = (acc + Vsum) / (2048 + rowsum) ----
  rsum += __shfl_xor(rsum, 16);
  rsum += __shfl_xor(rsum, 32);      // all 4 lh-copies now hold full sum for q=lm
  const float* vs = Vsum + (b * 4 + g) * 64;
  #pragma unroll
  for (int r = 0; r < 4; r++) {
    float den = __shfl(rsum, 4 * lh + r);   // row-sum for q = 4lh+r
    float inv = 1.f / (2048.f + den);
    int qrow = qt0 + wid * 16 + 4 * lh + r;
    float* op = Xb + (size_t)(b * 2048 + qrow) * 1024 + h * 64;
    #pragma unroll
    for (int di = 0; di < 4; di++)
      op[di * 16 + lm] = (acc[di][r] + vs[di * 16 + lm]) * inv;
  }
}

extern "C" void kernel_launch(void* const* d_in, const int* in_sizes, int n_in,
                              void* d_out, int out_size, void* d_ws, size_t ws_size,
                              hipStream_t stream) {
  const float* query = (const float*)d_in[0];
  const float* key   = (const float*)d_in[1];
  const float* value = (const float*)d_in[2];
  const float* Wq = (const float*)d_in[3];
  const float* bq = (const float*)d_in[4];
  const float* Wk = (const float*)d_in[5];
  const float* bk = (const float*)d_in[6];
  const float* Wv = (const float*)d_in[7];
  const float* bv = (const float*)d_in[8];
  const float* Wo = (const float*)d_in[9];
  const float* bo = (const float*)d_in[10];
  float* out = (float*)d_out;

  char* ws = (char*)d_ws;
  size_t off = 0;
  auto alloc = [&](size_t bytes) { size_t o = off; off += (bytes + 255) & ~(size_t)255; return o; };
  float* alphas   = (float*)(ws + alloc(16));
  float* partials = (float*)(ws + alloc(4 * 256 * 4));
  float* vsum     = (float*)(ws + alloc(8 * 64 * 4));
  float* invs     = (float*)(ws + alloc(4 * 4096 * 4));
  // sign-weight buffers contiguous (w_sign4 writes flat)
  unsigned short* wsq = (unsigned short*)(ws + alloc((size_t)1024 * 1024 * 2));
  unsigned short* wsk = (unsigned short*)(ws + alloc((size_t)256 * 1024 * 2));
  unsigned short* wsv = (unsigned short*)(ws + alloc((size_t)256 * 1024 * 2));
  unsigned short* wso = (unsigned short*)(ws + alloc((size_t)1024 * 1024 * 2));
  unsigned short* aq  = (unsigned short*)(ws + alloc((size_t)4096 * 1024 * 2)); // reused for ax
  unsigned short* akv = (unsigned short*)(ws + alloc((size_t)2 * 4096 * 1024 * 2)); // ak|av, reused as xbuf
  unsigned short* ak = akv;
  unsigned short* av = akv + (size_t)4096 * 1024;
  unsigned short* qb16 = (unsigned short*)(ws + alloc((size_t)4096 * 1024 * 2));
  unsigned short* kb16 = (unsigned short*)(ws + alloc((size_t)8 * 2048 * 64 * 2));
  unsigned short* vb16 = (unsigned short*)(ws + alloc((size_t)8 * 64 * 2048 * 2));
  float* xbuf = (float*)akv;   // 16MB overlay; ak/av dead after K/V GEMMs
  unsigned short* ax = aq;     // overlay; aq dead after Q GEMM

  absmean_stage1<<<dim3(256, 4), 256, 0, stream>>>(Wq, Wk, Wv, Wo, partials);
  absmean_stage2<<<4, 256, 0, stream>>>(partials, alphas);

  w_sign4<<<2560, 256, 0, stream>>>(Wq, Wk, Wv, Wo, wsq);

  act_quant3<<<dim3(4096, 3), 256, 0, stream>>>(query, key, value, aq, ak, av, invs);

  gemm_q<<<dim3(32, 16), 256, 0, stream>>>(aq, wsq, bq, invs + 0 * 4096, alphas, qb16);
  gemm_kv<<<dim3(32, 4, 2), 256, 0, stream>>>(ak, av, wsk, wsv, bk, bv,
                                              invs + 1 * 4096, invs + 2 * 4096,
                                              alphas, kb16, vb16);

  v_colsum_b<<<128, 256, 0, stream>>>(vb16, vsum);

  attn_mfma<<<dim3(16, 32), 512, 0, stream>>>(qb16, kb16, vb16, vsum, xbuf);

  act_quant1<<<4096, 256, 0, stream>>>(xbuf, ax, invs + 3 * 4096);
  gemm_o<<<dim3(32, 16), 256, 0, stream>>>(ax, wso, bo, invs + 3 * 4096, alphas, out);
}

// Round 6
// 144.588 us; speedup vs baseline: 35.7143x; 1.5459x over previous
//
#include <hip/hip_runtime.h>
#include <hip/hip_bf16.h>
#include <math.h>

typedef short bf16x8 __attribute__((ext_vector_type(8)));
typedef float f32x4 __attribute__((ext_vector_type(4)));

#define LOG2E 1.4426950408889634f

__device__ inline unsigned short f2bf(float x) {          // RNE
  __hip_bfloat16 h = __float2bfloat16(x);
  return *reinterpret_cast<unsigned short*>(&h);
}
__device__ inline unsigned f2bf2(float lo, float hi) {
  unsigned a = f2bf(lo), b = f2bf(hi);
  return a | (b << 16);
}
__device__ inline float bf2f(unsigned short u) {
  return __uint_as_float(((unsigned)u) << 16);
}
__device__ inline unsigned short f2bf_trunc(float x) {    // exact for small ints
  return (unsigned short)(__float_as_uint(x) >> 16);
}

__device__ inline void gload16(const void* g, void* l) {
  __builtin_amdgcn_global_load_lds((const __attribute__((address_space(1))) unsigned int*)g,
                                   (__attribute__((address_space(3))) unsigned int*)l, 16, 0, 0);
}

// ---------------- sign(W)->bf16 + per-block |W| partials (fused, one read of W) ----
__global__ void w_sign_absmean(const float* __restrict__ Wq, const float* __restrict__ Wk,
                               const float* __restrict__ Wv, const float* __restrict__ Wo,
                               unsigned short* __restrict__ out, float* __restrict__ partials) {
  int tid = threadIdx.x, lane = tid & 63, wid = tid >> 6;
  int i = blockIdx.x * 256 + tid;
  const float* W; int base;
  if (i < 262144)      { W = Wq; base = 0; }
  else if (i < 327680) { W = Wk; base = 262144; }
  else if (i < 393216) { W = Wv; base = 327680; }
  else                 { W = Wo; base = 393216; }
  float4 v = ((const float4*)W)[i - base];
  unsigned short s0 = (v.x > 0.f) ? 0x3F80 : (v.x < 0.f ? 0xBF80 : 0);
  unsigned short s1 = (v.y > 0.f) ? 0x3F80 : (v.y < 0.f ? 0xBF80 : 0);
  unsigned short s2 = (v.z > 0.f) ? 0x3F80 : (v.z < 0.f ? 0xBF80 : 0);
  unsigned short s3 = (v.w > 0.f) ? 0x3F80 : (v.w < 0.f ? 0xBF80 : 0);
  uint2 o;
  o.x = (unsigned)s0 | ((unsigned)s1 << 16);
  o.y = (unsigned)s2 | ((unsigned)s3 << 16);
  ((uint2*)out)[i] = o;
  float a = (fabsf(v.x) + fabsf(v.y)) + (fabsf(v.z) + fabsf(v.w));
  #pragma unroll
  for (int off = 32; off > 0; off >>= 1) a += __shfl_xor(a, off);
  __shared__ float rw[4];
  if (lane == 0) rw[wid] = a;
  __syncthreads();
  if (tid == 0) partials[blockIdx.x] = (rw[0] + rw[1]) + (rw[2] + rw[3]);
}

__global__ void absmean2(const float* __restrict__ partials, float* __restrict__ alphas) {
  int y = blockIdx.x, tid = threadIdx.x, lane = tid & 63, wid = tid >> 6;
  int start = (y == 0) ? 0 : (y == 1) ? 1024 : (y == 2) ? 1280 : 1536;
  int cnt = (y == 0 || y == 3) ? 1024 : 256;
  float s = 0.f;
  for (int i = tid; i < cnt; i += 256) s += partials[start + i];
  #pragma unroll
  for (int off = 32; off > 0; off >>= 1) s += __shfl_xor(s, off);
  __shared__ float rw[4];
  if (lane == 0) rw[wid] = s;
  __syncthreads();
  if (tid == 0) alphas[y] = ((rw[0] + rw[1]) + (rw[2] + rw[3])) / ((float)cnt * 1024.f);
}

// ---------------- RMSNorm + act quant (wave-shuffle, 1 barrier) ----------------
__device__ inline void act_quant_body(const float* __restrict__ X, unsigned short* __restrict__ Q,
                                      float* __restrict__ inv_s, int r) {
  int tid = threadIdx.x, lane = tid & 63, wid = tid >> 6;
  const float* x = X + (size_t)r * 1024;
  float4 v = ((const float4*)x)[tid];
  float ss = v.x * v.x + v.y * v.y + v.z * v.z + v.w * v.w;
  float am = fmaxf(fmaxf(fabsf(v.x), fabsf(v.y)), fmaxf(fabsf(v.z), fabsf(v.w)));
  #pragma unroll
  for (int off = 32; off > 0; off >>= 1) {
    ss += __shfl_xor(ss, off);
    am = fmaxf(am, __shfl_xor(am, off));
  }
  __shared__ float rs[4], rm[4];
  if (lane == 0) { rs[wid] = ss; rm[wid] = am; }
  __syncthreads();
  ss = (rs[0] + rs[1]) + (rs[2] + rs[3]);
  am = fmaxf(fmaxf(rm[0], rm[1]), fmaxf(rm[2], rm[3]));
  float rms = sqrtf(ss * (1.f / 1024.f) + 1e-6f);
  float inv_rms = 1.f / rms;
  float maxn = am * inv_rms * 0.03125f;
  float cm = fmaxf(maxn, 1e-5f);
  float mul = inv_rms * 0.03125f * (127.f / cm);
  float q0 = fminf(fmaxf(rintf(v.x * mul), -128.f), 127.f);
  float q1 = fminf(fmaxf(rintf(v.y * mul), -128.f), 127.f);
  float q2 = fminf(fmaxf(rintf(v.z * mul), -128.f), 127.f);
  float q3 = fminf(fmaxf(rintf(v.w * mul), -128.f), 127.f);
  uint2 o;
  o.x = (unsigned)f2bf_trunc(q0) | ((unsigned)f2bf_trunc(q1) << 16);
  o.y = (unsigned)f2bf_trunc(q2) | ((unsigned)f2bf_trunc(q3) << 16);
  ((uint2*)(Q + (size_t)r * 1024))[tid] = o;
  if (tid == 0) inv_s[r] = cm / 127.f;
}

__global__ void act_quant3(const float* __restrict__ X0, const float* __restrict__ X1,
                           const float* __restrict__ X2, unsigned short* __restrict__ Q0,
                           unsigned short* __restrict__ Q1, unsigned short* __restrict__ Q2,
                           float* __restrict__ invs) {
  int which = blockIdx.y;
  const float* X = (which == 0) ? X0 : (which == 1) ? X1 : X2;
  unsigned short* Q = (which == 0) ? Q0 : (which == 1) ? Q1 : Q2;
  act_quant_body(X, Q, invs + which * 4096, blockIdx.x);
}

__global__ void act_quant1(const float* __restrict__ X, unsigned short* __restrict__ Q,
                           float* __restrict__ inv_s) {
  act_quant_body(X, Q, inv_s, blockIdx.x);
}

// ---------------- LDS-staged bf16 MFMA bit-GEMM (global_load_lds, swizzled) ----
// EPI: 0 = fp32 [row][N]; 1 = bf16 [row][1024] * 0.125*log2e (Q); 2 = bf16 K [bg][t][64];
//      3 = bf16 V^T [bg][d][2048] via LDS transpose (coalesced stores)
template <int TM, int N, int EPI>
__device__ inline void gemm_lds_body(const unsigned short* __restrict__ A,
                                     const unsigned short* __restrict__ Wb,
                                     const float* __restrict__ bias,
                                     const float* __restrict__ inv_s,
                                     const float* __restrict__ alphas, int aidx,
                                     void* __restrict__ Outv) {
  constexpr int FM = TM / 32;                 // frags in M per wave (4 or 2)
  __shared__ __align__(16) unsigned short Sh[TM * 64 + 64 * 64];
  unsigned short* Al = Sh;                    // [TM][64] k-major, 16B-block swizzled
  unsigned short* Bl = Sh + TM * 64;          // [64][64]
  int tid = threadIdx.x, lane = tid & 63, wid = tid >> 6;
  int rb = blockIdx.x * TM, cb = blockIdx.y * 64;
  int wm = wid >> 1, wn = wid & 1;
  int lm = lane & 15, lh = lane >> 4;
  int l8 = lane >> 3, l7 = lane & 7;
  int sw = lm & 7;
  f32x4 acc[FM][2];
  #pragma unroll
  for (int i = 0; i < FM; i++) { acc[i][0] = (f32x4){0,0,0,0}; acc[i][1] = (f32x4){0,0,0,0}; }
  int scol = (l7 ^ l8) << 3;                  // pre-swizzled source col (shorts)
  const unsigned short* Ag = A + (size_t)(rb + l8) * 1024 + scol;
  const unsigned short* Bg = Wb + (size_t)(cb + l8) * 1024 + scol;
  int ro0 = ((0 * 4 + lh) ^ sw) << 3;         // swizzled k-offsets (shorts) per k-half
  int ro1 = ((1 * 4 + lh) ^ sw) << 3;
  for (int bk = 0; bk < 1024; bk += 64) {
    __syncthreads();
    #pragma unroll
    for (int c = 0; c < FM; c++) {            // A: TM/8 chunks over 4 waves
      int chunk = wid * FM + c;
      gload16(Ag + (size_t)chunk * 8 * 1024 + bk, &Al[chunk * 512]);
    }
    #pragma unroll
    for (int c = 0; c < 2; c++) {             // B: 8 chunks over 4 waves
      int chunk = wid * 2 + c;
      gload16(Bg + (size_t)chunk * 8 * 1024 + bk, &Bl[chunk * 512]);
    }
    __syncthreads();
    #pragma unroll
    for (int kh = 0; kh < 2; kh++) {
      int ro = kh ? ro1 : ro0;
      bf16x8 af[FM], bfr[2];
      #pragma unroll
      for (int i = 0; i < FM; i++)
        af[i] = *(const bf16x8*)&Al[(wm * FM * 16 + i * 16 + lm) * 64 + ro];
      #pragma unroll
      for (int j = 0; j < 2; j++)
        bfr[j] = *(const bf16x8*)&Bl[(wn * 32 + j * 16 + lm) * 64 + ro];
      #pragma unroll
      for (int i = 0; i < FM; i++)
        #pragma unroll
        for (int j = 0; j < 2; j++)
          acc[i][j] = __builtin_amdgcn_mfma_f32_16x16x32_bf16(af[i], bfr[j], acc[i][j], 0, 0, 0);
    }
  }
  float alpha = alphas[aidx];
  int lh4 = lh * 4;
  if (EPI == 3) {
    // transpose through LDS, then coalesced 128B-row stores
    unsigned short (*TL)[72] = (unsigned short(*)[72])Sh;   // 64 x 72 shorts
    __syncthreads();
    #pragma unroll
    for (int i = 0; i < FM; i++)
      #pragma unroll
      for (int r = 0; r < 4; r++) {
        int row = wm * FM * 16 + i * 16 + lh4 + r;          // local t
        float f = alpha * inv_s[rb + row];
        #pragma unroll
        for (int j = 0; j < 2; j++) {
          int col = wn * 32 + j * 16 + lm;                  // local d
          TL[col][row] = f2bf(f * acc[i][j][r] + bias[cb + col]);
        }
      }
    __syncthreads();
    int b = rb >> 11, t0 = rb & 2047, gI = cb >> 6;
    int dl = tid >> 2, toff = (tid & 3) * 16;
    unsigned short* op = (unsigned short*)Outv + (((size_t)(b * 4 + gI)) << 17) +
                         (size_t)dl * 2048 + t0 + toff;
    uint4 w0 = *(uint4*)&TL[dl][toff];
    uint4 w1 = *(uint4*)&TL[dl][toff + 8];
    *(uint4*)op = w0;
    *(uint4*)(op + 8) = w1;
  } else {
    #pragma unroll
    for (int i = 0; i < FM; i++) {
      #pragma unroll
      for (int r = 0; r < 4; r++) {
        int row = rb + wm * FM * 16 + i * 16 + lh4 + r;
        float f = alpha * inv_s[row];
        #pragma unroll
        for (int j = 0; j < 2; j++) {
          int col = cb + wn * 32 + j * 16 + lm;
          float val = f * acc[i][j][r] + bias[col];
          if (EPI == 0) {
            ((float*)Outv)[(size_t)row * N + col] = val;
          } else if (EPI == 1) {
            ((unsigned short*)Outv)[(size_t)row * 1024 + col] = f2bf(val * (0.125f * LOG2E));
          } else {   // EPI == 2: K layout
            int b = row >> 11, t = row & 2047, gg = col >> 6, d = col & 63;
            ((unsigned short*)Outv)[(((size_t)(b * 4 + gg)) << 17) + t * 64 + d] = f2bf(val);
          }
        }
      }
    }
  }
}

__global__ __launch_bounds__(256) void gemm_q(
    const unsigned short* __restrict__ A, const unsigned short* __restrict__ Wb,
    const float* __restrict__ bias, const float* __restrict__ inv_s,
    const float* __restrict__ alphas, unsigned short* __restrict__ Out) {
  gemm_lds_body<128, 1024, 1>(A, Wb, bias, inv_s, alphas, 0, Out);
}

__global__ __launch_bounds__(256) void gemm_kv(
    const unsigned short* __restrict__ A0, const unsigned short* __restrict__ A1,
    const unsigned short* __restrict__ W0, const unsigned short* __restrict__ W1,
    const float* __restrict__ b0, const float* __restrict__ b1,
    const float* __restrict__ is0, const float* __restrict__ is1,
    const float* __restrict__ alphas, unsigned short* __restrict__ K16,
    unsigned short* __restrict__ V16T) {
  if (blockIdx.z == 0) gemm_lds_body<64, 256, 2>(A0, W0, b0, is0, alphas, 1, K16);
  else                 gemm_lds_body<64, 256, 3>(A1, W1, b1, is1, alphas, 2, V16T);
}

__global__ __launch_bounds__(256) void gemm_o(
    const unsigned short* __restrict__ A, const unsigned short* __restrict__ Wb,
    const float* __restrict__ bias, const float* __restrict__ inv_s,
    const float* __restrict__ alphas, float* __restrict__ Out) {
  gemm_lds_body<128, 1024, 0>(A, Wb, bias, inv_s, alphas, 3, Out);
}

// ---------------- V column sums from V^T bf16 (contiguous rows) ----------------
__global__ void v_colsum_b(const unsigned short* __restrict__ VT, float* __restrict__ Vsum) {
  int row = blockIdx.x * 4 + (threadIdx.x >> 6);   // 0..511 = bg*64 + d
  int lane = threadIdx.x & 63;
  const unsigned short* p = VT + (size_t)row * 2048 + lane * 8;
  float s = 0.f;
  #pragma unroll
  for (int i = 0; i < 4; i++) {
    uint4 v = *(const uint4*)(p + i * 512);
    s += bf2f((unsigned short)(v.x)) + bf2f((unsigned short)(v.x >> 16));
    s += bf2f((unsigned short)(v.y)) + bf2f((unsigned short)(v.y >> 16));
    s += bf2f((unsigned short)(v.z)) + bf2f((unsigned short)(v.z >> 16));
    s += bf2f((unsigned short)(v.w)) + bf2f((unsigned short)(v.w >> 16));
  }
  #pragma unroll
  for (int off = 32; off > 0; off >>= 1) s += __shfl_xor(s, off);
  if (lane == 0) Vsum[row] = s;
}

// ---------------- GQA attention: swapped QK^T, reg P~, dbuf LDS, MFMA rowsum ----
// grid (bh=32, qtile=16): same-bh blocks share an XCD (id%8) -> K/V L2-resident.
__global__ __launch_bounds__(512, 4) void attn_mfma(
    const unsigned short* __restrict__ Qb, const unsigned short* __restrict__ Kb,
    const unsigned short* __restrict__ Vb, const float* __restrict__ Vsum,
    float* __restrict__ Xb) {
  __shared__ __align__(16) unsigned short Kl[2][64 * 64];
  __shared__ __align__(16) unsigned short Vt[2][64 * 64];
  int tid = threadIdx.x, lane = tid & 63, wid = tid >> 6;
  int bh = blockIdx.x; int b = bh >> 4, h = bh & 15, g = h >> 2;
  int qt0 = blockIdx.y * 128;
  int lm = lane & 15, lh = lane >> 4;
  int m7 = lm & 7, h1 = lh >> 1, h0 = lh & 1;

  // Q fragments (scale 0.125*log2e folded by gemm_q)
  bf16x8 qf[2];
  {
    const unsigned short* qp = Qb + (size_t)(b * 2048 + qt0 + wid * 16 + lm) * 1024 + h * 64 + lh * 8;
    qf[0] = *(const bf16x8*)(qp);
    qf[1] = *(const bf16x8*)(qp + 32);
  }

  f32x4 zero = {0.f, 0.f, 0.f, 0.f};
  f32x4 acc[4];
  #pragma unroll
  for (int i = 0; i < 4; i++) acc[i] = zero;
  f32x4 accl = zero;                 // row-sum accumulator (via ones-MFMA)
  const short ONE = 0x3F80;
  bf16x8 ones = {ONE, ONE, ONE, ONE, ONE, ONE, ONE, ONE};

  // staging: thread stages one 16B block of K and one of V per tile (source pre-swizzled)
  int s_t = tid >> 3, s_u = tid & 7;
  int s_swz = (s_u ^ (s_t & 7)) << 3;
  const unsigned short* kgb = Kb + (((size_t)(b * 4 + g)) << 17) + s_t * 64 + s_swz;
  const unsigned short* vgb = Vb + (((size_t)(b * 4 + g)) << 17) + (size_t)s_t * 2048 + s_swz;
  int sd = s_t * 64 + s_u * 8;

  // swizzled read offsets (shorts)
  int ko0 = lm * 64 + ((lh ^ m7) << 3);
  int ko1 = lm * 64 + (((4 + lh) ^ m7) << 3);
  int vo00 = lm * 64 + (((0 + h1) ^ m7) << 3) + h0 * 4;
  int vo01 = lm * 64 + (((2 + h1) ^ m7) << 3) + h0 * 4;
  int vo10 = lm * 64 + (((4 + h1) ^ m7) << 3) + h0 * 4;
  int vo11 = lm * 64 + (((6 + h1) ^ m7) << 3) + h0 * 4;

  auto compute = [&](const unsigned short* Kbuf, const unsigned short* Vbuf) {
    f32x4 sv[4];
    #pragma unroll
    for (int ti = 0; ti < 4; ti++) {
      bf16x8 k0 = *(const bf16x8*)&Kbuf[ko0 + ti * 1024];
      bf16x8 k1 = *(const bf16x8*)&Kbuf[ko1 + ti * 1024];
      f32x4 z = zero;
      z = __builtin_amdgcn_mfma_f32_16x16x32_bf16(k0, qf[0], z, 0, 0, 0);
      z = __builtin_amdgcn_mfma_f32_16x16x32_bf16(k1, qf[1], z, 0, 0, 0);
      sv[ti] = z;
    }
    unsigned pk[4][2];
    #pragma unroll
    for (int ti = 0; ti < 4; ti++) {
      float p0 = exp2f(sv[ti][0]) - 1.f;
      float p1 = exp2f(sv[ti][1]) - 1.f;
      float p2 = exp2f(sv[ti][2]) - 1.f;
      float p3 = exp2f(sv[ti][3]) - 1.f;
      pk[ti][0] = f2bf2(p0, p1);
      pk[ti][1] = f2bf2(p2, p3);
    }
    #pragma unroll
    for (int kk = 0; kk < 2; kk++) {
      union { bf16x8 v; unsigned u[4]; } pf;
      pf.u[0] = pk[2 * kk][0];     pf.u[1] = pk[2 * kk][1];
      pf.u[2] = pk[2 * kk + 1][0]; pf.u[3] = pk[2 * kk + 1][1];
      accl = __builtin_amdgcn_mfma_f32_16x16x32_bf16(pf.v, ones, accl, 0, 0, 0);
      int va = kk ? vo10 : vo00, vb2 = kk ? vo11 : vo01;
      #pragma unroll
      for (int di = 0; di < 4; di++) {
        union { bf16x8 v; uint2 q[2]; } vf;
        vf.q[0] = *(const uint2*)&Vbuf[va + di * 1024];
        vf.q[1] = *(const uint2*)&Vbuf[vb2 + di * 1024];
        acc[di] = __builtin_amdgcn_mfma_f32_16x16x32_bf16(pf.v, vf.v, acc[di], 0, 0, 0);
      }
    }
  };

  // prologue: tiles 0,1 into regs; tile 0 -> buf0
  uint4 krA = *(const uint4*)(kgb), vrA = *(const uint4*)(vgb);
  uint4 krB = *(const uint4*)(kgb + 4096), vrB = *(const uint4*)(vgb + 64);
  *(uint4*)&Kl[0][sd] = krA; *(uint4*)&Vt[0][sd] = vrA;
  __syncthreads();

  for (int it = 0; it < 32; it += 2) {
    int tn = (it + 2 < 32) ? it + 2 : 31;
    krA = *(const uint4*)(kgb + (size_t)tn * 4096);
    vrA = *(const uint4*)(vgb + (size_t)tn * 64);
    *(uint4*)&Kl[1][sd] = krB; *(uint4*)&Vt[1][sd] = vrB;
    compute(Kl[0], Vt[0]);
    __syncthreads();
    int tn2 = (it + 3 < 32) ? it + 3 : 31;
    krB = *(const uint4*)(kgb + (size_t)tn2 * 4096);
    vrB = *(const uint4*)(vgb + (size_t)tn2 * 64);
    *(uint4*)&Kl[0][sd] = krA; *(uint4*)&Vt[0][sd] = vrA;
    compute(Kl[1], Vt[1]);
    __syncthreads();
  }

  // epilogue: out = (acc + Vsum) / (2048 + rowsum); accl[r] = rowsum(q=4lh+r)
  const float* vs = Vsum + (b * 4 + g) * 64;
  #pragma unroll
  for (int r = 0; r < 4; r++) {
    float inv = 1.f / (2048.f + accl[r]);
    int qrow = qt0 + wid * 16 + 4 * lh + r;
    float* op = Xb + (size_t)(b * 2048 + qrow) * 1024 + h * 64;
    #pragma unroll
    for (int di = 0; di < 4; di++)
      op[di * 16 + lm] = (acc[di][r] + vs[di * 16 + lm]) * inv;
  }
}

extern "C" void kernel_launch(void* const* d_in, const int* in_sizes, int n_in,
                              void* d_out, int out_size, void* d_ws, size_t ws_size,
                              hipStream_t stream) {
  const float* query = (const float*)d_in[0];
  const float* key   = (const float*)d_in[1];
  const float* value = (const float*)d_in[2];
  const float* Wq = (const float*)d_in[3];
  const float* bq = (const float*)d_in[4];
  const float* Wk = (const float*)d_in[5];
  const float* bk = (const float*)d_in[6];
  const float* Wv = (const float*)d_in[7];
  const float* bv = (const float*)d_in[8];
  const float* Wo = (const float*)d_in[9];
  const float* bo = (const float*)d_in[10];
  float* out = (float*)d_out;

  char* ws = (char*)d_ws;
  size_t off = 0;
  auto alloc = [&](size_t bytes) { size_t o = off; off += (bytes + 255) & ~(size_t)255; return o; };
  float* alphas   = (float*)(ws + alloc(16));
  float* partials = (float*)(ws + alloc(2560 * 4));
  float* vsum     = (float*)(ws + alloc(8 * 64 * 4));
  float* invs     = (float*)(ws + alloc(4 * 4096 * 4));
  // sign-weight buffers contiguous (w_sign_absmean writes flat)
  unsigned short* wsq = (unsigned short*)(ws + alloc((size_t)1024 * 1024 * 2));
  unsigned short* wsk = (unsigned short*)(ws + alloc((size_t)256 * 1024 * 2));
  unsigned short* wsv = (unsigned short*)(ws + alloc((size_t)256 * 1024 * 2));
  unsigned short* wso = (unsigned short*)(ws + alloc((size_t)1024 * 1024 * 2));
  unsigned short* aq  = (unsigned short*)(ws + alloc((size_t)4096 * 1024 * 2)); // reused for ax
  unsigned short* akv = (unsigned short*)(ws + alloc((size_t)2 * 4096 * 1024 * 2)); // ak|av, reused as xbuf
  unsigned short* ak = akv;
  unsigned short* av = akv + (size_t)4096 * 1024;
  unsigned short* qb16 = (unsigned short*)(ws + alloc((size_t)4096 * 1024 * 2));
  unsigned short* kb16 = (unsigned short*)(ws + alloc((size_t)8 * 2048 * 64 * 2));
  unsigned short* vb16 = (unsigned short*)(ws + alloc((size_t)8 * 64 * 2048 * 2));
  float* xbuf = (float*)akv;   // 16MB overlay; ak/av dead after K/V GEMMs
  unsigned short* ax = aq;     // overlay; aq dead after Q GEMM

  w_sign_absmean<<<2560, 256, 0, stream>>>(Wq, Wk, Wv, Wo, wsq, partials);
  absmean2<<<4, 256, 0, stream>>>(partials, alphas);

  act_quant3<<<dim3(4096, 3), 256, 0, stream>>>(query, key, value, aq, ak, av, invs);

  gemm_q<<<dim3(32, 16), 256, 0, stream>>>(aq, wsq, bq, invs + 0 * 4096, alphas, qb16);
  gemm_kv<<<dim3(64, 4, 2), 256, 0, stream>>>(ak, av, wsk, wsv, bk, bv,
                                              invs + 1 * 4096, invs + 2 * 4096,
                                              alphas, kb16, vb16);

  v_colsum_b<<<128, 256, 0, stream>>>(vb16, vsum);

  attn_mfma<<<dim3(32, 16), 512, 0, stream>>>(qb16, kb16, vb16, vsum, xbuf);

  act_quant1<<<4096, 256, 0, stream>>>(xbuf, ax, invs + 3 * 4096);
  gemm_o<<<dim3(32, 16), 256, 0, stream>>>(ax, wso, bo, invs + 3 * 4096, alphas, out);
}

// Round 7
// 122.802 us; speedup vs baseline: 42.0505x; 1.1774x over previous
//
#include <hip/hip_runtime.h>
#include <hip/hip_bf16.h>
#include <math.h>

typedef short bf16x8 __attribute__((ext_vector_type(8)));
typedef float f32x4 __attribute__((ext_vector_type(4)));

__device__ inline unsigned short f2bf(float x) {          // RNE
  __hip_bfloat16 h = __float2bfloat16(x);
  return *reinterpret_cast<unsigned short*>(&h);
}
__device__ inline unsigned f2bf2(float lo, float hi) {    // packed RNE pair
  union { __hip_bfloat162 h; unsigned u; } cv;
  cv.h = __float22bfloat162_rn(make_float2(lo, hi));
  return cv.u;
}
__device__ inline float bf2f(unsigned short u) {
  return __uint_as_float(((unsigned)u) << 16);
}
__device__ inline unsigned short f2bf_trunc(float x) {    // exact for small ints
  return (unsigned short)(__float_as_uint(x) >> 16);
}

__device__ inline void gload16(const void* g, void* l) {
  __builtin_amdgcn_global_load_lds((const __attribute__((address_space(1))) unsigned int*)g,
                                   (__attribute__((address_space(3))) unsigned int*)l, 16, 0, 0);
}

// ---------------- sign(W)->bf16 + per-block |W| partials (fused) ----------------
__global__ void w_sign_absmean(const float* __restrict__ Wq, const float* __restrict__ Wk,
                               const float* __restrict__ Wv, const float* __restrict__ Wo,
                               unsigned short* __restrict__ out, float* __restrict__ partials) {
  int tid = threadIdx.x, lane = tid & 63, wid = tid >> 6;
  int i = blockIdx.x * 256 + tid;
  const float* W; int base;
  if (i < 262144)      { W = Wq; base = 0; }
  else if (i < 327680) { W = Wk; base = 262144; }
  else if (i < 393216) { W = Wv; base = 327680; }
  else                 { W = Wo; base = 393216; }
  float4 v = ((const float4*)W)[i - base];
  unsigned short s0 = (v.x > 0.f) ? 0x3F80 : (v.x < 0.f ? 0xBF80 : 0);
  unsigned short s1 = (v.y > 0.f) ? 0x3F80 : (v.y < 0.f ? 0xBF80 : 0);
  unsigned short s2 = (v.z > 0.f) ? 0x3F80 : (v.z < 0.f ? 0xBF80 : 0);
  unsigned short s3 = (v.w > 0.f) ? 0x3F80 : (v.w < 0.f ? 0xBF80 : 0);
  uint2 o;
  o.x = (unsigned)s0 | ((unsigned)s1 << 16);
  o.y = (unsigned)s2 | ((unsigned)s3 << 16);
  ((uint2*)out)[i] = o;
  float a = (fabsf(v.x) + fabsf(v.y)) + (fabsf(v.z) + fabsf(v.w));
  #pragma unroll
  for (int off = 32; off > 0; off >>= 1) a += __shfl_xor(a, off);
  __shared__ float rw[4];
  if (lane == 0) rw[wid] = a;
  __syncthreads();
  if (tid == 0) partials[blockIdx.x] = (rw[0] + rw[1]) + (rw[2] + rw[3]);
}

__global__ void absmean2(const float* __restrict__ partials, float* __restrict__ alphas) {
  int y = blockIdx.x, tid = threadIdx.x, lane = tid & 63, wid = tid >> 6;
  int start = (y == 0) ? 0 : (y == 1) ? 1024 : (y == 2) ? 1280 : 1536;
  int cnt = (y == 0 || y == 3) ? 1024 : 256;
  float s = 0.f;
  for (int i = tid; i < cnt; i += 256) s += partials[start + i];
  #pragma unroll
  for (int off = 32; off > 0; off >>= 1) s += __shfl_xor(s, off);
  __shared__ float rw[4];
  if (lane == 0) rw[wid] = s;
  __syncthreads();
  if (tid == 0) alphas[y] = ((rw[0] + rw[1]) + (rw[2] + rw[3])) / ((float)cnt * 1024.f);
}

// ---------------- RMSNorm + act quant core (wave-shuffle, 1 barrier) ------------
__device__ inline void act_quant_core(float4 v, unsigned short* __restrict__ Q,
                                      float* __restrict__ inv_s, int r) {
  int tid = threadIdx.x, lane = tid & 63, wid = tid >> 6;
  float ss = v.x * v.x + v.y * v.y + v.z * v.z + v.w * v.w;
  float am = fmaxf(fmaxf(fabsf(v.x), fabsf(v.y)), fmaxf(fabsf(v.z), fabsf(v.w)));
  #pragma unroll
  for (int off = 32; off > 0; off >>= 1) {
    ss += __shfl_xor(ss, off);
    am = fmaxf(am, __shfl_xor(am, off));
  }
  __shared__ float rs[4], rm[4];
  if (lane == 0) { rs[wid] = ss; rm[wid] = am; }
  __syncthreads();
  ss = (rs[0] + rs[1]) + (rs[2] + rs[3]);
  am = fmaxf(fmaxf(rm[0], rm[1]), fmaxf(rm[2], rm[3]));
  float rms = sqrtf(ss * (1.f / 1024.f) + 1e-6f);
  float inv_rms = 1.f / rms;
  float maxn = am * inv_rms * 0.03125f;
  float cm = fmaxf(maxn, 1e-5f);
  float mul = inv_rms * 0.03125f * (127.f / cm);
  float q0 = fminf(fmaxf(rintf(v.x * mul), -128.f), 127.f);
  float q1 = fminf(fmaxf(rintf(v.y * mul), -128.f), 127.f);
  float q2 = fminf(fmaxf(rintf(v.z * mul), -128.f), 127.f);
  float q3 = fminf(fmaxf(rintf(v.w * mul), -128.f), 127.f);
  uint2 o;
  o.x = (unsigned)f2bf_trunc(q0) | ((unsigned)f2bf_trunc(q1) << 16);
  o.y = (unsigned)f2bf_trunc(q2) | ((unsigned)f2bf_trunc(q3) << 16);
  ((uint2*)(Q + (size_t)r * 1024))[tid] = o;
  if (tid == 0) inv_s[r] = cm / 127.f;
}

__global__ void act_quant3(const float* __restrict__ X0, const float* __restrict__ X1,
                           const float* __restrict__ X2, unsigned short* __restrict__ Q0,
                           unsigned short* __restrict__ Q1, unsigned short* __restrict__ Q2,
                           float* __restrict__ invs) {
  int which = blockIdx.y;
  const float* X = (which == 0) ? X0 : (which == 1) ? X1 : X2;
  unsigned short* Q = (which == 0) ? Q0 : (which == 1) ? Q1 : Q2;
  int r = blockIdx.x;
  float4 v = ((const float4*)(X + (size_t)r * 1024))[threadIdx.x];
  act_quant_core(v, Q, invs + which * 4096, r);
}

__global__ void act_quant1b(const unsigned short* __restrict__ X, unsigned short* __restrict__ Q,
                            float* __restrict__ inv_s) {
  int r = blockIdx.x;
  uint2 raw = ((const uint2*)(X + (size_t)r * 1024))[threadIdx.x];
  float4 v;
  v.x = bf2f((unsigned short)raw.x); v.y = bf2f((unsigned short)(raw.x >> 16));
  v.z = bf2f((unsigned short)raw.y); v.w = bf2f((unsigned short)(raw.y >> 16));
  act_quant_core(v, Q, inv_s, r);
}

// ---------------- LDS-staged bf16 MFMA bit-GEMM (global_load_lds, swizzled) ----
// EPI: 0 = fp32 [row][N]; 1 = bf16 [row][1024] * 0.125 (Q); 2 = bf16 K [bg][t][64];
//      3 = bf16 V^T [bg][d][2048] with t-columns permuted within 32-groups
template <int TM, int N, int EPI>
__device__ inline void gemm_lds_body(const unsigned short* __restrict__ A,
                                     const unsigned short* __restrict__ Wb,
                                     const float* __restrict__ bias,
                                     const float* __restrict__ inv_s,
                                     const float* __restrict__ alphas, int aidx,
                                     void* __restrict__ Outv) {
  constexpr int FM = TM / 32;
  __shared__ __align__(16) unsigned short Sh[TM * 64 + 64 * 64];
  unsigned short* Al = Sh;
  unsigned short* Bl = Sh + TM * 64;
  int tid = threadIdx.x, lane = tid & 63, wid = tid >> 6;
  int rb = blockIdx.x * TM, cb = blockIdx.y * 64;
  int wm = wid >> 1, wn = wid & 1;
  int lm = lane & 15, lh = lane >> 4;
  int l8 = lane >> 3, l7 = lane & 7;
  int sw = lm & 7;
  f32x4 acc[FM][2];
  #pragma unroll
  for (int i = 0; i < FM; i++) { acc[i][0] = (f32x4){0,0,0,0}; acc[i][1] = (f32x4){0,0,0,0}; }
  int scol = (l7 ^ l8) << 3;
  const unsigned short* Ag = A + (size_t)(rb + l8) * 1024 + scol;
  const unsigned short* Bg = Wb + (size_t)(cb + l8) * 1024 + scol;
  int ro0 = ((0 * 4 + lh) ^ sw) << 3;
  int ro1 = ((1 * 4 + lh) ^ sw) << 3;
  for (int bk = 0; bk < 1024; bk += 64) {
    __syncthreads();
    #pragma unroll
    for (int c = 0; c < FM; c++) {
      int chunk = wid * FM + c;
      gload16(Ag + (size_t)chunk * 8 * 1024 + bk, &Al[chunk * 512]);
    }
    #pragma unroll
    for (int c = 0; c < 2; c++) {
      int chunk = wid * 2 + c;
      gload16(Bg + (size_t)chunk * 8 * 1024 + bk, &Bl[chunk * 512]);
    }
    __syncthreads();
    #pragma unroll
    for (int kh = 0; kh < 2; kh++) {
      int ro = kh ? ro1 : ro0;
      bf16x8 af[FM], bfr[2];
      #pragma unroll
      for (int i = 0; i < FM; i++)
        af[i] = *(const bf16x8*)&Al[(wm * FM * 16 + i * 16 + lm) * 64 + ro];
      #pragma unroll
      for (int j = 0; j < 2; j++)
        bfr[j] = *(const bf16x8*)&Bl[(wn * 32 + j * 16 + lm) * 64 + ro];
      #pragma unroll
      for (int i = 0; i < FM; i++)
        #pragma unroll
        for (int j = 0; j < 2; j++)
          acc[i][j] = __builtin_amdgcn_mfma_f32_16x16x32_bf16(af[i], bfr[j], acc[i][j], 0, 0, 0);
    }
  }
  float alpha = alphas[aidx];
  int lh4 = lh * 4;
  if (EPI == 3) {
    unsigned short (*TL)[72] = (unsigned short(*)[72])Sh;   // 64 x 72 shorts (9KB < Sh)
    __syncthreads();
    #pragma unroll
    for (int i = 0; i < FM; i++)
      #pragma unroll
      for (int r = 0; r < 4; r++) {
        int row = wm * FM * 16 + i * 16 + lh4 + r;          // local logical t
        float f = alpha * inv_s[rb + row];
        // PV-friendly permutation: phys = (row&32) | lh_*8 | s*4 | r
        int pr = (row & 32) | (((row >> 2) & 3) << 3) | (((row >> 4) & 1) << 2) | (row & 3);
        #pragma unroll
        for (int j = 0; j < 2; j++) {
          int col = wn * 32 + j * 16 + lm;                  // local d
          TL[col][pr] = f2bf(f * acc[i][j][r] + bias[cb + col]);
        }
      }
    __syncthreads();
    int b = rb >> 11, t0 = rb & 2047, gI = cb >> 6;
    int dl = tid >> 2, toff = (tid & 3) * 16;
    unsigned short* op = (unsigned short*)Outv + (((size_t)(b * 4 + gI)) << 17) +
                         (size_t)dl * 2048 + t0 + toff;
    uint4 w0 = *(uint4*)&TL[dl][toff];
    uint4 w1 = *(uint4*)&TL[dl][toff + 8];
    *(uint4*)op = w0;
    *(uint4*)(op + 8) = w1;
  } else {
    #pragma unroll
    for (int i = 0; i < FM; i++) {
      #pragma unroll
      for (int r = 0; r < 4; r++) {
        int row = rb + wm * FM * 16 + i * 16 + lh4 + r;
        float f = alpha * inv_s[row];
        #pragma unroll
        for (int j = 0; j < 2; j++) {
          int col = cb + wn * 32 + j * 16 + lm;
          float val = f * acc[i][j][r] + bias[col];
          if (EPI == 0) {
            ((float*)Outv)[(size_t)row * N + col] = val;
          } else if (EPI == 1) {
            ((unsigned short*)Outv)[(size_t)row * 1024 + col] = f2bf(val * 0.125f);
          } else {   // EPI == 2: K layout
            int b = row >> 11, t = row & 2047, gg = col >> 6, d = col & 63;
            ((unsigned short*)Outv)[(((size_t)(b * 4 + gg)) << 17) + t * 64 + d] = f2bf(val);
          }
        }
      }
    }
  }
}

__global__ __launch_bounds__(256) void gemm_q(
    const unsigned short* __restrict__ A, const unsigned short* __restrict__ Wb,
    const float* __restrict__ bias, const float* __restrict__ inv_s,
    const float* __restrict__ alphas, unsigned short* __restrict__ Out) {
  gemm_lds_body<128, 1024, 1>(A, Wb, bias, inv_s, alphas, 0, Out);
}

__global__ __launch_bounds__(256) void gemm_kv(
    const unsigned short* __restrict__ A0, const unsigned short* __restrict__ A1,
    const unsigned short* __restrict__ W0, const unsigned short* __restrict__ W1,
    const float* __restrict__ b0, const float* __restrict__ b1,
    const float* __restrict__ is0, const float* __restrict__ is1,
    const float* __restrict__ alphas, unsigned short* __restrict__ K16,
    unsigned short* __restrict__ V16T) {
  if (blockIdx.z == 0) gemm_lds_body<64, 256, 2>(A0, W0, b0, is0, alphas, 1, K16);
  else                 gemm_lds_body<64, 256, 3>(A1, W1, b1, is1, alphas, 2, V16T);
}

__global__ __launch_bounds__(256) void gemm_o(
    const unsigned short* __restrict__ A, const unsigned short* __restrict__ Wb,
    const float* __restrict__ bias, const float* __restrict__ inv_s,
    const float* __restrict__ alphas, float* __restrict__ Out) {
  gemm_lds_body<128, 1024, 0>(A, Wb, bias, inv_s, alphas, 3, Out);
}

// ---------------- V column sums from V^T bf16 (order-independent) ----------------
__global__ void v_colsum_b(const unsigned short* __restrict__ VT, float* __restrict__ Vsum) {
  int row = blockIdx.x * 4 + (threadIdx.x >> 6);
  int lane = threadIdx.x & 63;
  const unsigned short* p = VT + (size_t)row * 2048 + lane * 8;
  float s = 0.f;
  #pragma unroll
  for (int i = 0; i < 4; i++) {
    uint4 v = *(const uint4*)(p + i * 512);
    s += bf2f((unsigned short)(v.x)) + bf2f((unsigned short)(v.x >> 16));
    s += bf2f((unsigned short)(v.y)) + bf2f((unsigned short)(v.y >> 16));
    s += bf2f((unsigned short)(v.z)) + bf2f((unsigned short)(v.z >> 16));
    s += bf2f((unsigned short)(v.w)) + bf2f((unsigned short)(v.w >> 16));
  }
  #pragma unroll
  for (int off = 32; off > 0; off >>= 1) s += __shfl_xor(s, off);
  if (lane == 0) Vsum[row] = s;
}

// ---------------- GQA attention: swapped QK^T, reg P~, dbuf, b128 V reads -------
__global__ __launch_bounds__(512, 4) void attn_mfma(
    const unsigned short* __restrict__ Qb, const unsigned short* __restrict__ Kb,
    const unsigned short* __restrict__ Vb, const float* __restrict__ Vsum,
    unsigned short* __restrict__ Xb) {
  __shared__ __align__(16) unsigned short Kl[2][64 * 64];
  __shared__ __align__(16) unsigned short Vt[2][64 * 64];
  int tid = threadIdx.x, lane = tid & 63, wid = tid >> 6;
  int bh = blockIdx.x; int b = bh >> 4, h = bh & 15, g = h >> 2;
  int qt0 = blockIdx.y * 128;
  int lm = lane & 15, lh = lane >> 4;
  int m7 = lm & 7;

  bf16x8 qf[2];
  {
    const unsigned short* qp = Qb + (size_t)(b * 2048 + qt0 + wid * 16 + lm) * 1024 + h * 64 + lh * 8;
    qf[0] = *(const bf16x8*)(qp);
    qf[1] = *(const bf16x8*)(qp + 32);
  }

  f32x4 zero = {0.f, 0.f, 0.f, 0.f};
  f32x4 acc[4];
  #pragma unroll
  for (int i = 0; i < 4; i++) acc[i] = zero;
  f32x4 accl = zero;
  const short ONE = 0x3F80;
  bf16x8 ones = {ONE, ONE, ONE, ONE, ONE, ONE, ONE, ONE};

  int s_t = tid >> 3, s_u = tid & 7;
  int s_swz = (s_u ^ (s_t & 7)) << 3;
  const unsigned short* kgb = Kb + (((size_t)(b * 4 + g)) << 17) + s_t * 64 + s_swz;
  const unsigned short* vgb = Vb + (((size_t)(b * 4 + g)) << 17) + (size_t)s_t * 2048 + s_swz;
  int sd = s_t * 64 + s_u * 8;

  // K-frag and V-frag swizzled read offsets (shorts): block (kk*4+lh) ^ m7
  int ko0 = lm * 64 + ((lh ^ m7) << 3);
  int ko1 = lm * 64 + (((4 + lh) ^ m7) << 3);

  auto compute = [&](const unsigned short* Kbuf, const unsigned short* Vbuf) {
    f32x4 sv[4];
    __builtin_amdgcn_s_setprio(1);
    #pragma unroll
    for (int ti = 0; ti < 4; ti++) {
      bf16x8 k0 = *(const bf16x8*)&Kbuf[ko0 + ti * 1024];
      bf16x8 k1 = *(const bf16x8*)&Kbuf[ko1 + ti * 1024];
      f32x4 z = zero;
      z = __builtin_amdgcn_mfma_f32_16x16x32_bf16(k0, qf[0], z, 0, 0, 0);
      z = __builtin_amdgcn_mfma_f32_16x16x32_bf16(k1, qf[1], z, 0, 0, 0);
      sv[ti] = z;
    }
    __builtin_amdgcn_s_setprio(0);
    unsigned pk[4][2];
    #pragma unroll
    for (int ti = 0; ti < 4; ti++) {
      float p0 = __expf(sv[ti][0]) - 1.f;
      float p1 = __expf(sv[ti][1]) - 1.f;
      float p2 = __expf(sv[ti][2]) - 1.f;
      float p3 = __expf(sv[ti][3]) - 1.f;
      pk[ti][0] = f2bf2(p0, p1);
      pk[ti][1] = f2bf2(p2, p3);
    }
    __builtin_amdgcn_s_setprio(1);
    #pragma unroll
    for (int kk = 0; kk < 2; kk++) {
      union { bf16x8 v; unsigned u[4]; } pf;
      pf.u[0] = pk[2 * kk][0];     pf.u[1] = pk[2 * kk][1];
      pf.u[2] = pk[2 * kk + 1][0]; pf.u[3] = pk[2 * kk + 1][1];
      accl = __builtin_amdgcn_mfma_f32_16x16x32_bf16(pf.v, ones, accl, 0, 0, 0);
      int vo = kk ? ko1 : ko0;     // same swizzle family as K (block kk*4+lh ^ m7)
      #pragma unroll
      for (int di = 0; di < 4; di++) {
        bf16x8 vf = *(const bf16x8*)&Vbuf[vo + di * 1024];
        acc[di] = __builtin_amdgcn_mfma_f32_16x16x32_bf16(pf.v, vf, acc[di], 0, 0, 0);
      }
    }
    __builtin_amdgcn_s_setprio(0);
  };

  uint4 krA = *(const uint4*)(kgb), vrA = *(const uint4*)(vgb);
  uint4 krB = *(const uint4*)(kgb + 4096), vrB = *(const uint4*)(vgb + 64);
  *(uint4*)&Kl[0][sd] = krA; *(uint4*)&Vt[0][sd] = vrA;
  __syncthreads();

  for (int it = 0; it < 32; it += 2) {
    int tn = (it + 2 < 32) ? it + 2 : 31;
    krA = *(const uint4*)(kgb + (size_t)tn * 4096);
    vrA = *(const uint4*)(vgb + (size_t)tn * 64);
    *(uint4*)&Kl[1][sd] = krB; *(uint4*)&Vt[1][sd] = vrB;
    compute(Kl[0], Vt[0]);
    __syncthreads();
    int tn2 = (it + 3 < 32) ? it + 3 : 31;
    krB = *(const uint4*)(kgb + (size_t)tn2 * 4096);
    vrB = *(const uint4*)(vgb + (size_t)tn2 * 64);
    *(uint4*)&Kl[0][sd] = krA; *(uint4*)&Vt[0][sd] = vrA;
    compute(Kl[1], Vt[1]);
    __syncthreads();
  }

  const float* vs = Vsum + (b * 4 + g) * 64;
  #pragma unroll
  for (int r = 0; r < 4; r++) {
    float inv = 1.f / (2048.f + accl[r]);
    int qrow = qt0 + wid * 16 + 4 * lh + r;
    unsigned short* op = Xb + (size_t)(b * 2048 + qrow) * 1024 + h * 64;
    #pragma unroll
    for (int di = 0; di < 4; di++)
      op[di * 16 + lm] = f2bf((acc[di][r] + vs[di * 16 + lm]) * inv);
  }
}

extern "C" void kernel_launch(void* const* d_in, const int* in_sizes, int n_in,
                              void* d_out, int out_size, void* d_ws, size_t ws_size,
                              hipStream_t stream) {
  const float* query = (const float*)d_in[0];
  const float* key   = (const float*)d_in[1];
  const float* value = (const float*)d_in[2];
  const float* Wq = (const float*)d_in[3];
  const float* bq = (const float*)d_in[4];
  const float* Wk = (const float*)d_in[5];
  const float* bk = (const float*)d_in[6];
  const float* Wv = (const float*)d_in[7];
  const float* bv = (const float*)d_in[8];
  const float* Wo = (const float*)d_in[9];
  const float* bo = (const float*)d_in[10];
  float* out = (float*)d_out;

  char* ws = (char*)d_ws;
  size_t off = 0;
  auto alloc = [&](size_t bytes) { size_t o = off; off += (bytes + 255) & ~(size_t)255; return o; };
  float* alphas   = (float*)(ws + alloc(16));
  float* partials = (float*)(ws + alloc(2560 * 4));
  float* vsum     = (float*)(ws + alloc(8 * 64 * 4));
  float* invs     = (float*)(ws + alloc(4 * 4096 * 4));
  unsigned short* wsq = (unsigned short*)(ws + alloc((size_t)1024 * 1024 * 2));
  unsigned short* wsk = (unsigned short*)(ws + alloc((size_t)256 * 1024 * 2));
  unsigned short* wsv = (unsigned short*)(ws + alloc((size_t)256 * 1024 * 2));
  unsigned short* wso = (unsigned short*)(ws + alloc((size_t)1024 * 1024 * 2));
  unsigned short* aq  = (unsigned short*)(ws + alloc((size_t)4096 * 1024 * 2)); // reused for ax
  unsigned short* akv = (unsigned short*)(ws + alloc((size_t)2 * 4096 * 1024 * 2)); // ak|av, reused as xbuf
  unsigned short* ak = akv;
  unsigned short* av = akv + (size_t)4096 * 1024;
  unsigned short* qb16 = (unsigned short*)(ws + alloc((size_t)4096 * 1024 * 2));
  unsigned short* kb16 = (unsigned short*)(ws + alloc((size_t)8 * 2048 * 64 * 2));
  unsigned short* vb16 = (unsigned short*)(ws + alloc((size_t)8 * 64 * 2048 * 2));
  unsigned short* xbuf = akv;  // bf16 attn out overlay; ak/av dead after K/V GEMMs
  unsigned short* ax = aq;     // overlay; aq dead after Q GEMM

  w_sign_absmean<<<2560, 256, 0, stream>>>(Wq, Wk, Wv, Wo, wsq, partials);
  absmean2<<<4, 256, 0, stream>>>(partials, alphas);

  act_quant3<<<dim3(4096, 3), 256, 0, stream>>>(query, key, value, aq, ak, av, invs);

  gemm_q<<<dim3(32, 16), 256, 0, stream>>>(aq, wsq, bq, invs + 0 * 4096, alphas, qb16);
  gemm_kv<<<dim3(64, 4, 2), 256, 0, stream>>>(ak, av, wsk, wsv, bk, bv,
                                              invs + 1 * 4096, invs + 2 * 4096,
                                              alphas, kb16, vb16);

  v_colsum_b<<<128, 256, 0, stream>>>(vb16, vsum);

  attn_mfma<<<dim3(32, 16), 512, 0, stream>>>(qb16, kb16, vb16, vsum, xbuf);

  act_quant1b<<<4096, 256, 0, stream>>>(xbuf, ax, invs + 3 * 4096);
  gemm_o<<<dim3(32, 16), 256, 0, stream>>>(ax, wso, bo, invs + 3 * 4096, alphas, out);
}

// Round 8
// 102.871 us; speedup vs baseline: 50.1977x; 1.1937x over previous
//
#include <hip/hip_runtime.h>
#include <hip/hip_bf16.h>
#include <math.h>

typedef short bf16x8 __attribute__((ext_vector_type(8)));
typedef float f32x4 __attribute__((ext_vector_type(4)));
typedef int i32x4 __attribute__((ext_vector_type(4)));

#define LOG2E 1.4426950408889634f

__device__ inline unsigned short f2bf(float x) {          // RNE
  __hip_bfloat16 h = __float2bfloat16(x);
  return *reinterpret_cast<unsigned short*>(&h);
}
__device__ inline unsigned f2bf2(float lo, float hi) {    // packed RNE pair
  union { __hip_bfloat162 h; unsigned u; } cv;
  cv.h = __float22bfloat162_rn(make_float2(lo, hi));
  return cv.u;
}
__device__ inline float bf2f(unsigned short u) {
  return __uint_as_float(((unsigned)u) << 16);
}

__device__ inline void gload16(const void* g, void* l) {
  __builtin_amdgcn_global_load_lds((const __attribute__((address_space(1))) unsigned int*)g,
                                   (__attribute__((address_space(3))) unsigned int*)l, 16, 0, 0);
}

// ---------------- sign(W)->i8 + per-block |W| partials (fused) ----------------
__global__ void w_sign_absmean(const float* __restrict__ Wq, const float* __restrict__ Wk,
                               const float* __restrict__ Wv, const float* __restrict__ Wo,
                               signed char* __restrict__ out, float* __restrict__ partials) {
  int tid = threadIdx.x, lane = tid & 63, wid = tid >> 6;
  int i = blockIdx.x * 256 + tid;
  const float* W; int base;
  if (i < 262144)      { W = Wq; base = 0; }
  else if (i < 327680) { W = Wk; base = 262144; }
  else if (i < 393216) { W = Wv; base = 327680; }
  else                 { W = Wo; base = 393216; }
  float4 v = ((const float4*)W)[i - base];
  int s0 = (v.x > 0.f) ? 1 : (v.x < 0.f ? -1 : 0);
  int s1 = (v.y > 0.f) ? 1 : (v.y < 0.f ? -1 : 0);
  int s2 = (v.z > 0.f) ? 1 : (v.z < 0.f ? -1 : 0);
  int s3 = (v.w > 0.f) ? 1 : (v.w < 0.f ? -1 : 0);
  ((unsigned*)out)[i] = (s0 & 0xff) | ((s1 & 0xff) << 8) | ((s2 & 0xff) << 16) | ((s3 & 0xff) << 24);
  float a = (fabsf(v.x) + fabsf(v.y)) + (fabsf(v.z) + fabsf(v.w));
  #pragma unroll
  for (int off = 32; off > 0; off >>= 1) a += __shfl_xor(a, off);
  __shared__ float rw[4];
  if (lane == 0) rw[wid] = a;
  __syncthreads();
  if (tid == 0) partials[blockIdx.x] = (rw[0] + rw[1]) + (rw[2] + rw[3]);
}

__global__ void absmean2(const float* __restrict__ partials, float* __restrict__ alphas) {
  int y = blockIdx.x, tid = threadIdx.x, lane = tid & 63, wid = tid >> 6;
  int start = (y == 0) ? 0 : (y == 1) ? 1024 : (y == 2) ? 1280 : 1536;
  int cnt = (y == 0 || y == 3) ? 1024 : 256;
  float s = 0.f;
  for (int i = tid; i < cnt; i += 256) s += partials[start + i];
  #pragma unroll
  for (int off = 32; off > 0; off >>= 1) s += __shfl_xor(s, off);
  __shared__ float rw[4];
  if (lane == 0) rw[wid] = s;
  __syncthreads();
  if (tid == 0) alphas[y] = ((rw[0] + rw[1]) + (rw[2] + rw[3])) / ((float)cnt * 1024.f);
}

// ---------------- RMSNorm + act quant -> int8 (wave-shuffle, 1 barrier) ---------
__device__ inline void act_quant_core(float4 v, signed char* __restrict__ Q,
                                      float* __restrict__ inv_s, int r) {
  int tid = threadIdx.x, lane = tid & 63, wid = tid >> 6;
  float ss = v.x * v.x + v.y * v.y + v.z * v.z + v.w * v.w;
  float am = fmaxf(fmaxf(fabsf(v.x), fabsf(v.y)), fmaxf(fabsf(v.z), fabsf(v.w)));
  #pragma unroll
  for (int off = 32; off > 0; off >>= 1) {
    ss += __shfl_xor(ss, off);
    am = fmaxf(am, __shfl_xor(am, off));
  }
  __shared__ float rs[4], rm[4];
  if (lane == 0) { rs[wid] = ss; rm[wid] = am; }
  __syncthreads();
  ss = (rs[0] + rs[1]) + (rs[2] + rs[3]);
  am = fmaxf(fmaxf(rm[0], rm[1]), fmaxf(rm[2], rm[3]));
  float rms = sqrtf(ss * (1.f / 1024.f) + 1e-6f);
  float inv_rms = 1.f / rms;
  float maxn = am * inv_rms * 0.03125f;
  float cm = fmaxf(maxn, 1e-5f);
  float mul = inv_rms * 0.03125f * (127.f / cm);
  int q0 = (int)fminf(fmaxf(rintf(v.x * mul), -128.f), 127.f);
  int q1 = (int)fminf(fmaxf(rintf(v.y * mul), -128.f), 127.f);
  int q2 = (int)fminf(fmaxf(rintf(v.z * mul), -128.f), 127.f);
  int q3 = (int)fminf(fmaxf(rintf(v.w * mul), -128.f), 127.f);
  unsigned o = (q0 & 0xff) | ((q1 & 0xff) << 8) | ((q2 & 0xff) << 16) | ((q3 & 0xff) << 24);
  ((unsigned*)(Q + (size_t)r * 1024))[tid] = o;
  if (tid == 0) inv_s[r] = cm / 127.f;
}

__global__ void act_quant3(const float* __restrict__ X0, const float* __restrict__ X1,
                           const float* __restrict__ X2, signed char* __restrict__ Q0,
                           signed char* __restrict__ Q1, signed char* __restrict__ Q2,
                           float* __restrict__ invs) {
  int which = blockIdx.y;
  const float* X = (which == 0) ? X0 : (which == 1) ? X1 : X2;
  signed char* Q = (which == 0) ? Q0 : (which == 1) ? Q1 : Q2;
  int r = blockIdx.x;
  float4 v = ((const float4*)(X + (size_t)r * 1024))[threadIdx.x];
  act_quant_core(v, Q, invs + which * 4096, r);
}

__global__ void act_quant1b(const unsigned short* __restrict__ X, signed char* __restrict__ Q,
                            float* __restrict__ inv_s) {
  int r = blockIdx.x;
  uint2 raw = ((const uint2*)(X + (size_t)r * 1024))[threadIdx.x];
  float4 v;
  v.x = bf2f((unsigned short)raw.x); v.y = bf2f((unsigned short)(raw.x >> 16));
  v.z = bf2f((unsigned short)raw.y); v.w = bf2f((unsigned short)(raw.y >> 16));
  act_quant_core(v, Q, inv_s, r);
}

// ---------------- LDS-staged i8 MFMA bit-GEMM (exact int32 accumulation) --------
// EPI: 0 = fp32 [row][N]; 1 = bf16 [row][1024] * 0.125*log2e (Q); 2 = bf16 K [bg][t][64];
//      3 = bf16 V^T [bg][d][2048] with t-columns permuted within 32-groups
template <int TM, int N, int EPI>
__device__ inline void gemm_lds_body(const signed char* __restrict__ A,
                                     const signed char* __restrict__ Wb,
                                     const float* __restrict__ bias,
                                     const float* __restrict__ inv_s,
                                     const float* __restrict__ alphas, int aidx,
                                     void* __restrict__ Outv) {
  constexpr int FM = TM / 32;
  __shared__ __align__(16) signed char Sh[TM * 128 + 64 * 128];
  signed char* Al = Sh;                       // [TM][128B], 16B-block XOR swizzled
  signed char* Bl = Sh + TM * 128;            // [64][128B]
  int tid = threadIdx.x, lane = tid & 63, wid = tid >> 6;
  int rb = blockIdx.x * TM, cb = blockIdx.y * 64;
  int wm = wid >> 1, wn = wid & 1;
  int lm = lane & 15, lh = lane >> 4;
  int l8 = lane >> 3, l7 = lane & 7;
  int sw = lm & 7;
  i32x4 acc[FM][2];
  #pragma unroll
  for (int i = 0; i < FM; i++) { acc[i][0] = (i32x4){0,0,0,0}; acc[i][1] = (i32x4){0,0,0,0}; }
  const signed char* Ag = A + (size_t)(rb + l8) * 1024 + ((l7 ^ l8) << 4);
  const signed char* Bg = Wb + (size_t)(cb + l8) * 1024 + ((l7 ^ l8) << 4);
  int ko0 = ((0 * 4 + lh) ^ sw) << 4;         // swizzled 16B-block offsets per K=64 half
  int ko1 = ((1 * 4 + lh) ^ sw) << 4;
  for (int bk = 0; bk < 1024; bk += 128) {
    __syncthreads();
    #pragma unroll
    for (int c = 0; c < FM; c++) {            // A: TM/8 8-row chunks over 4 waves
      int chunk = wid * FM + c;
      gload16(Ag + (size_t)chunk * 8 * 1024 + bk, &Al[chunk * 1024]);
    }
    #pragma unroll
    for (int c = 0; c < 2; c++) {             // B: 8 chunks over 4 waves
      int chunk = wid * 2 + c;
      gload16(Bg + (size_t)chunk * 8 * 1024 + bk, &Bl[chunk * 1024]);
    }
    __syncthreads();
    #pragma unroll
    for (int kh = 0; kh < 2; kh++) {
      int ko = kh ? ko1 : ko0;
      i32x4 af[FM], bfr[2];
      #pragma unroll
      for (int i = 0; i < FM; i++)
        af[i] = *(const i32x4*)&Al[(wm * FM * 16 + i * 16 + lm) * 128 + ko];
      #pragma unroll
      for (int j = 0; j < 2; j++)
        bfr[j] = *(const i32x4*)&Bl[(wn * 32 + j * 16 + lm) * 128 + ko];
      #pragma unroll
      for (int i = 0; i < FM; i++)
        #pragma unroll
        for (int j = 0; j < 2; j++)
          acc[i][j] = __builtin_amdgcn_mfma_i32_16x16x64_i8(af[i], bfr[j], acc[i][j], 0, 0, 0);
    }
  }
  float alpha = alphas[aidx];
  int lh4 = lh * 4;
  if (EPI == 3) {
    unsigned short (*TL)[72] = (unsigned short(*)[72])Sh;   // 64 x 72 shorts (9KB < Sh)
    __syncthreads();
    #pragma unroll
    for (int i = 0; i < FM; i++)
      #pragma unroll
      for (int r = 0; r < 4; r++) {
        int row = wm * FM * 16 + i * 16 + lh4 + r;          // local logical t
        float f = alpha * inv_s[rb + row];
        int pr = (row & 32) | (((row >> 2) & 3) << 3) | (((row >> 4) & 1) << 2) | (row & 3);
        #pragma unroll
        for (int j = 0; j < 2; j++) {
          int col = wn * 32 + j * 16 + lm;                  // local d
          TL[col][pr] = f2bf(f * (float)acc[i][j][r] + bias[cb + col]);
        }
      }
    __syncthreads();
    int b = rb >> 11, t0 = rb & 2047, gI = cb >> 6;
    int dl = tid >> 2, toff = (tid & 3) * 16;
    unsigned short* op = (unsigned short*)Outv + (((size_t)(b * 4 + gI)) << 17) +
                         (size_t)dl * 2048 + t0 + toff;
    uint4 w0 = *(uint4*)&TL[dl][toff];
    uint4 w1 = *(uint4*)&TL[dl][toff + 8];
    *(uint4*)op = w0;
    *(uint4*)(op + 8) = w1;
  } else {
    #pragma unroll
    for (int i = 0; i < FM; i++) {
      #pragma unroll
      for (int r = 0; r < 4; r++) {
        int row = rb + wm * FM * 16 + i * 16 + lh4 + r;
        float f = alpha * inv_s[row];
        #pragma unroll
        for (int j = 0; j < 2; j++) {
          int col = cb + wn * 32 + j * 16 + lm;
          float val = f * (float)acc[i][j][r] + bias[col];
          if (EPI == 0) {
            ((float*)Outv)[(size_t)row * N + col] = val;
          } else if (EPI == 1) {
            ((unsigned short*)Outv)[(size_t)row * 1024 + col] = f2bf(val * (0.125f * LOG2E));
          } else {   // EPI == 2: K layout
            int b = row >> 11, t = row & 2047, gg = col >> 6, d = col & 63;
            ((unsigned short*)Outv)[(((size_t)(b * 4 + gg)) << 17) + t * 64 + d] = f2bf(val);
          }
        }
      }
    }
  }
}

__global__ __launch_bounds__(256) void gemm_q(
    const signed char* __restrict__ A, const signed char* __restrict__ Wb,
    const float* __restrict__ bias, const float* __restrict__ inv_s,
    const float* __restrict__ alphas, unsigned short* __restrict__ Out) {
  gemm_lds_body<128, 1024, 1>(A, Wb, bias, inv_s, alphas, 0, Out);
}

__global__ __launch_bounds__(256) void gemm_kv(
    const signed char* __restrict__ A0, const signed char* __restrict__ A1,
    const signed char* __restrict__ W0, const signed char* __restrict__ W1,
    const float* __restrict__ b0, const float* __restrict__ b1,
    const float* __restrict__ is0, const float* __restrict__ is1,
    const float* __restrict__ alphas, unsigned short* __restrict__ K16,
    unsigned short* __restrict__ V16T) {
  if (blockIdx.z == 0) gemm_lds_body<64, 256, 2>(A0, W0, b0, is0, alphas, 1, K16);
  else                 gemm_lds_body<64, 256, 3>(A1, W1, b1, is1, alphas, 2, V16T);
}

__global__ __launch_bounds__(256) void gemm_o(
    const signed char* __restrict__ A, const signed char* __restrict__ Wb,
    const float* __restrict__ bias, const float* __restrict__ inv_s,
    const float* __restrict__ alphas, float* __restrict__ Out) {
  gemm_lds_body<128, 1024, 0>(A, Wb, bias, inv_s, alphas, 3, Out);
}

// ---------------- V column sums from V^T bf16 (order-independent) ----------------
__global__ void v_colsum_b(const unsigned short* __restrict__ VT, float* __restrict__ Vsum) {
  int row = blockIdx.x * 4 + (threadIdx.x >> 6);
  int lane = threadIdx.x & 63;
  const unsigned short* p = VT + (size_t)row * 2048 + lane * 8;
  float s = 0.f;
  #pragma unroll
  for (int i = 0; i < 4; i++) {
    uint4 v = *(const uint4*)(p + i * 512);
    s += bf2f((unsigned short)(v.x)) + bf2f((unsigned short)(v.x >> 16));
    s += bf2f((unsigned short)(v.y)) + bf2f((unsigned short)(v.y >> 16));
    s += bf2f((unsigned short)(v.z)) + bf2f((unsigned short)(v.z >> 16));
    s += bf2f((unsigned short)(v.w)) + bf2f((unsigned short)(v.w >> 16));
  }
  #pragma unroll
  for (int off = 32; off > 0; off >>= 1) s += __shfl_xor(s, off);
  if (lane == 0) Vsum[row] = s;
}

// ---------------- GQA attention: swapped QK^T, reg P~, dbuf, b128 V reads -------
__global__ __launch_bounds__(512, 4) void attn_mfma(
    const unsigned short* __restrict__ Qb, const unsigned short* __restrict__ Kb,
    const unsigned short* __restrict__ Vb, const float* __restrict__ Vsum,
    unsigned short* __restrict__ Xb) {
  __shared__ __align__(16) unsigned short Kl[2][64 * 64];
  __shared__ __align__(16) unsigned short Vt[2][64 * 64];
  int tid = threadIdx.x, lane = tid & 63, wid = tid >> 6;
  int bh = blockIdx.x; int b = bh >> 4, h = bh & 15, g = h >> 2;
  int qt0 = blockIdx.y * 128;
  int lm = lane & 15, lh = lane >> 4;
  int m7 = lm & 7;

  bf16x8 qf[2];
  {
    const unsigned short* qp = Qb + (size_t)(b * 2048 + qt0 + wid * 16 + lm) * 1024 + h * 64 + lh * 8;
    qf[0] = *(const bf16x8*)(qp);
    qf[1] = *(const bf16x8*)(qp + 32);
  }

  f32x4 zero = {0.f, 0.f, 0.f, 0.f};
  f32x4 acc[4];
  #pragma unroll
  for (int i = 0; i < 4; i++) acc[i] = zero;
  f32x4 accl = zero;
  const short ONE = 0x3F80;
  bf16x8 ones = {ONE, ONE, ONE, ONE, ONE, ONE, ONE, ONE};

  int s_t = tid >> 3, s_u = tid & 7;
  int s_swz = (s_u ^ (s_t & 7)) << 3;
  const unsigned short* kgb = Kb + (((size_t)(b * 4 + g)) << 17) + s_t * 64 + s_swz;
  const unsigned short* vgb = Vb + (((size_t)(b * 4 + g)) << 17) + (size_t)s_t * 2048 + s_swz;
  int sd = s_t * 64 + s_u * 8;

  int ko0 = lm * 64 + ((lh ^ m7) << 3);
  int ko1 = lm * 64 + (((4 + lh) ^ m7) << 3);

  auto compute = [&](const unsigned short* Kbuf, const unsigned short* Vbuf) {
    f32x4 sv[4];
    __builtin_amdgcn_s_setprio(1);
    #pragma unroll
    for (int ti = 0; ti < 4; ti++) {
      bf16x8 k0 = *(const bf16x8*)&Kbuf[ko0 + ti * 1024];
      bf16x8 k1 = *(const bf16x8*)&Kbuf[ko1 + ti * 1024];
      f32x4 z = zero;
      z = __builtin_amdgcn_mfma_f32_16x16x32_bf16(k0, qf[0], z, 0, 0, 0);
      z = __builtin_amdgcn_mfma_f32_16x16x32_bf16(k1, qf[1], z, 0, 0, 0);
      sv[ti] = z;
    }
    __builtin_amdgcn_s_setprio(0);
    unsigned pk[4][2];
    #pragma unroll
    for (int ti = 0; ti < 4; ti++) {
      float p0 = __builtin_amdgcn_exp2f(sv[ti][0]) - 1.f;
      float p1 = __builtin_amdgcn_exp2f(sv[ti][1]) - 1.f;
      float p2 = __builtin_amdgcn_exp2f(sv[ti][2]) - 1.f;
      float p3 = __builtin_amdgcn_exp2f(sv[ti][3]) - 1.f;
      pk[ti][0] = f2bf2(p0, p1);
      pk[ti][1] = f2bf2(p2, p3);
    }
    __builtin_amdgcn_s_setprio(1);
    #pragma unroll
    for (int kk = 0; kk < 2; kk++) {
      union { bf16x8 v; unsigned u[4]; } pf;
      pf.u[0] = pk[2 * kk][0];     pf.u[1] = pk[2 * kk][1];
      pf.u[2] = pk[2 * kk + 1][0]; pf.u[3] = pk[2 * kk + 1][1];
      accl = __builtin_amdgcn_mfma_f32_16x16x32_bf16(pf.v, ones, accl, 0, 0, 0);
      int vo = kk ? ko1 : ko0;
      #pragma unroll
      for (int di = 0; di < 4; di++) {
        bf16x8 vf = *(const bf16x8*)&Vbuf[vo + di * 1024];
        acc[di] = __builtin_amdgcn_mfma_f32_16x16x32_bf16(pf.v, vf, acc[di], 0, 0, 0);
      }
    }
    __builtin_amdgcn_s_setprio(0);
  };

  uint4 krA = *(const uint4*)(kgb), vrA = *(const uint4*)(vgb);
  uint4 krB = *(const uint4*)(kgb + 4096), vrB = *(const uint4*)(vgb + 64);
  *(uint4*)&Kl[0][sd] = krA; *(uint4*)&Vt[0][sd] = vrA;
  __syncthreads();

  for (int it = 0; it < 32; it += 2) {
    int tn = (it + 2 < 32) ? it + 2 : 31;
    krA = *(const uint4*)(kgb + (size_t)tn * 4096);
    vrA = *(const uint4*)(vgb + (size_t)tn * 64);
    *(uint4*)&Kl[1][sd] = krB; *(uint4*)&Vt[1][sd] = vrB;
    compute(Kl[0], Vt[0]);
    __syncthreads();
    int tn2 = (it + 3 < 32) ? it + 3 : 31;
    krB = *(const uint4*)(kgb + (size_t)tn2 * 4096);
    vrB = *(const uint4*)(vgb + (size_t)tn2 * 64);
    *(uint4*)&Kl[0][sd] = krA; *(uint4*)&Vt[0][sd] = vrA;
    compute(Kl[1], Vt[1]);
    __syncthreads();
  }

  const float* vs = Vsum + (b * 4 + g) * 64;
  #pragma unroll
  for (int r = 0; r < 4; r++) {
    float inv = 1.f / (2048.f + accl[r]);
    int qrow = qt0 + wid * 16 + 4 * lh + r;
    unsigned short* op = Xb + (size_t)(b * 2048 + qrow) * 1024 + h * 64;
    #pragma unroll
    for (int di = 0; di < 4; di++)
      op[di * 16 + lm] = f2bf((acc[di][r] + vs[di * 16 + lm]) * inv);
  }
}

extern "C" void kernel_launch(void* const* d_in, const int* in_sizes, int n_in,
                              void* d_out, int out_size, void* d_ws, size_t ws_size,
                              hipStream_t stream) {
  const float* query = (const float*)d_in[0];
  const float* key   = (const float*)d_in[1];
  const float* value = (const float*)d_in[2];
  const float* Wq = (const float*)d_in[3];
  const float* bq = (const float*)d_in[4];
  const float* Wk = (const float*)d_in[5];
  const float* bk = (const float*)d_in[6];
  const float* Wv = (const float*)d_in[7];
  const float* bv = (const float*)d_in[8];
  const float* Wo = (const float*)d_in[9];
  const float* bo = (const float*)d_in[10];
  float* out = (float*)d_out;

  char* ws = (char*)d_ws;
  size_t off = 0;
  auto alloc = [&](size_t bytes) { size_t o = off; off += (bytes + 255) & ~(size_t)255; return o; };
  float* alphas   = (float*)(ws + alloc(16));
  float* partials = (float*)(ws + alloc(2560 * 4));
  float* vsum     = (float*)(ws + alloc(8 * 64 * 4));
  float* invs     = (float*)(ws + alloc(4 * 4096 * 4));
  // sign-weight buffers contiguous (w_sign_absmean writes flat): i8 now
  signed char* wsq = (signed char*)(ws + alloc((size_t)1024 * 1024));
  signed char* wsk = (signed char*)(ws + alloc((size_t)256 * 1024));
  signed char* wsv = (signed char*)(ws + alloc((size_t)256 * 1024));
  signed char* wso = (signed char*)(ws + alloc((size_t)1024 * 1024));
  signed char* aq  = (signed char*)(ws + alloc((size_t)4096 * 1024));       // reused for ax
  signed char* akv = (signed char*)(ws + alloc((size_t)2 * 4096 * 1024));   // ak|av, reused as xbuf
  signed char* ak = akv;
  signed char* av = akv + (size_t)4096 * 1024;
  unsigned short* qb16 = (unsigned short*)(ws + alloc((size_t)4096 * 1024 * 2));
  unsigned short* kb16 = (unsigned short*)(ws + alloc((size_t)8 * 2048 * 64 * 2));
  unsigned short* vb16 = (unsigned short*)(ws + alloc((size_t)8 * 64 * 2048 * 2));
  unsigned short* xbuf = (unsigned short*)akv;  // bf16 attn out overlay (8MB, fits ak+av)
  signed char* ax = aq;                          // overlay; aq dead after Q GEMM

  w_sign_absmean<<<2560, 256, 0, stream>>>(Wq, Wk, Wv, Wo, wsq, partials);
  absmean2<<<4, 256, 0, stream>>>(partials, alphas);

  act_quant3<<<dim3(4096, 3), 256, 0, stream>>>(query, key, value, aq, ak, av, invs);

  gemm_q<<<dim3(32, 16), 256, 0, stream>>>(aq, wsq, bq, invs + 0 * 4096, alphas, qb16);
  gemm_kv<<<dim3(64, 4, 2), 256, 0, stream>>>(ak, av, wsk, wsv, bk, bv,
                                              invs + 1 * 4096, invs + 2 * 4096,
                                              alphas, kb16, vb16);

  v_colsum_b<<<128, 256, 0, stream>>>(vb16, vsum);

  attn_mfma<<<dim3(32, 16), 512, 0, stream>>>(qb16, kb16, vb16, vsum, xbuf);

  act_quant1b<<<4096, 256, 0, stream>>>(xbuf, ax, invs + 3 * 4096);
  gemm_o<<<dim3(32, 16), 256, 0, stream>>>(ax, wso, bo, invs + 3 * 4096, alphas, out);
}